// Round 7
// baseline (2914.993 us; speedup 1.0000x reference)
//
#include <hip/hip_runtime.h>
#include <hip/hip_bf16.h>

#define NN 100000
#define NE 1600000
#define NP 500000
#define C 128
#define NBUCK 782              // buckets of 128 dst nodes: 782*128 = 100096 >= NN

typedef __attribute__((ext_vector_type(8))) short bf16x8;
typedef __attribute__((ext_vector_type(4))) float f32x4;

__device__ inline unsigned short bfbits(float x) {
    __hip_bfloat16 h = __float2bfloat16(x);
    union { __hip_bfloat16 h; unsigned short u; } v; v.h = h;
    return v.u;
}
__device__ inline float bf2f(unsigned short b) {
    return __uint_as_float(((unsigned)b) << 16);
}

// split 8 consecutive f32 into bf16 hi + bf16 lo fragments
__device__ inline void split8(const float* p, bf16x8& hi, bf16x8& lo) {
    union { unsigned short s[8]; bf16x8 v; } uh, ul;
    f32x4 a = *(const f32x4*)p;
    f32x4 b = *(const f32x4*)(p + 4);
    float xs[8] = {a.x, a.y, a.z, a.w, b.x, b.y, b.z, b.w};
#pragma unroll
    for (int j = 0; j < 8; ++j) {
        unsigned short h = bfbits(xs[j]);
        uh.s[j] = h;
        ul.s[j] = bfbits(xs[j] - bf2f(h));
    }
    hi = uh.v;
    lo = ul.v;
}

// ---------- bucket counting + per-node degree ----------
__global__ __launch_bounds__(256) void bin_count_kernel(
        const int* __restrict__ dst, int* __restrict__ gcnt,
        int* __restrict__ deg, int nE) {
    __shared__ int h[NBUCK];
    int tid = threadIdx.x;
    for (int i = tid; i < NBUCK; i += 256) h[i] = 0;
    __syncthreads();
    int base = blockIdx.x * 8192;
#pragma unroll
    for (int j = 0; j < 32; ++j) {
        int e = base + tid + j * 256;
        if (e < nE) {
            int d = dst[e];
            atomicAdd(&h[d >> 7], 1);
            atomicAdd(&deg[d], 1);
        }
    }
    __syncthreads();
    for (int i = tid; i < NBUCK; i += 256)
        if (h[i]) atomicAdd(&gcnt[i], h[i]);
}

// ---------- scan bucket counts (one block) ----------
__global__ __launch_bounds__(1024) void bin_scan_kernel(
        const int* __restrict__ gcnt, int* __restrict__ gstart,
        int* __restrict__ gcursor) {
    __shared__ int s[1024];
    int tid = threadIdx.x;
    int v = (tid < NBUCK) ? gcnt[tid] : 0;
    s[tid] = v;
    __syncthreads();
    for (int off = 1; off < 1024; off <<= 1) {
        int t = (tid >= off) ? s[tid - off] : 0;
        __syncthreads();
        s[tid] += t;
        __syncthreads();
    }
    int excl = s[tid] - v;
    if (tid < NBUCK) { gstart[tid] = excl; gcursor[tid] = excl; }
    if (tid == NBUCK - 1) gstart[NBUCK] = excl + v;
}

// ---------- LDS-staged multisplit scatter: coalesced bucket-grouped writes ----------
__global__ __launch_bounds__(256) void bin_scatter_kernel(
        const int* __restrict__ src, const int* __restrict__ dst,
        int* __restrict__ gcursor, unsigned* __restrict__ elist, int nE) {
    __shared__ unsigned stage[4096];
    __shared__ unsigned short sbkt[4096];
    __shared__ int h[NBUCK];
    __shared__ int ex[NBUCK];
    __shared__ int gb[NBUCK];
    __shared__ int psum[256];
    int tid = threadIdx.x;
    for (int i = tid; i < NBUCK; i += 256) h[i] = 0;
    __syncthreads();
    int base = blockIdx.x * 4096;
    unsigned pk[16]; int bk[16];
#pragma unroll
    for (int j = 0; j < 16; ++j) {
        int e = base + tid + j * 256;
        bool ok = e < nE;
        int d = ok ? dst[e] : 0;
        int s = ok ? src[e] : 0;
        bk[j] = ok ? (d >> 7) : -1;
        pk[j] = ((unsigned)(d & 127) << 17) | (unsigned)s;
        if (ok) atomicAdd(&h[bk[j]], 1);
    }
    __syncthreads();
    // block-local exclusive scan over NBUCK (4 per thread)
    int lo = tid * 4;
    int c4[4]; int sum = 0;
#pragma unroll
    for (int j = 0; j < 4; ++j) {
        int idx = lo + j;
        c4[j] = (idx < NBUCK) ? h[idx] : 0;
        sum += c4[j];
    }
    psum[tid] = sum;
    __syncthreads();
    for (int off = 1; off < 256; off <<= 1) {
        int t = (tid >= off) ? psum[tid - off] : 0;
        __syncthreads();
        psum[tid] += t;
        __syncthreads();
    }
    int run = psum[tid] - sum;
#pragma unroll
    for (int j = 0; j < 4; ++j) {
        int idx = lo + j;
        if (idx < NBUCK) ex[idx] = run;
        run += c4[j];
    }
    __syncthreads();
    // reserve global space per bucket
    for (int i = tid; i < NBUCK; i += 256)
        if (h[i] > 0) gb[i] = atomicAdd(&gcursor[i], h[i]);
    // reset h as local cursor
    for (int i = tid; i < NBUCK; i += 256) h[i] = 0;
    __syncthreads();
#pragma unroll
    for (int j = 0; j < 16; ++j) {
        if (bk[j] >= 0) {
            int r = ex[bk[j]] + atomicAdd(&h[bk[j]], 1);
            stage[r] = pk[j];
            sbkt[r] = (unsigned short)bk[j];
        }
    }
    __syncthreads();
    int tot = min(4096, nE - base);
    for (int i = tid; i < tot; i += 256) {
        int b = sbkt[i];
        elist[gb[b] + (i - ex[b])] = stage[i];
    }
}

// ---------- compose decode projection into layer-2 weights ----------
__global__ void compose_kernel(const float* __restrict__ w2l, const float* __restrict__ w2r,
                               const float* __restrict__ b2,
                               const float* __restrict__ wd1, const float* __restrict__ bd1,
                               float* __restrict__ wcomp, float* __restrict__ bcomp) {
    int c = threadIdx.x;
    int k = blockIdx.x;
    if (k < C) {
        float wma = 0, wmb = 0, wha = 0, whb = 0;
        for (int j = 0; j < C; ++j) {
            float wt = wd1[j * C + c];
            float wb = wd1[(C + j) * C + c];
            float l = w2l[k * C + j];
            float r = w2r[k * C + j];
            wma += l * wt; wmb += l * wb;
            wha += r * wt; whb += r * wb;
        }
        wcomp[0 * C * C + k * C + c] = wma;
        wcomp[1 * C * C + k * C + c] = wha;
        wcomp[2 * C * C + k * C + c] = wmb;
        wcomp[3 * C * C + k * C + c] = whb;
    } else {
        float ba = bd1[c], bb = 0;
        for (int j = 0; j < C; ++j) {
            float bj = b2[j];
            ba += bj * wd1[j * C + c];
            bb += bj * wd1[(C + j) * C + c];
        }
        bcomp[c] = ba;
        bcomp[C + c] = bb;
    }
}

// ---------- pack W1=[wl;wr] (K=256,N=128) into B-fragment layout, bf16 hi/lo ----------
__global__ void pack_w1_kernel(const float* __restrict__ wl, const float* __restrict__ wr,
                               short* __restrict__ Wh, short* __restrict__ Wl) {
    int t = blockIdx.x * 256 + threadIdx.x;
    int j = t & 7, l = (t >> 3) & 63;
    int kf = (t >> 9) & 7;
    int nf = t >> 12;
    int k = kf * 32 + ((l >> 4) << 3) + j;
    int n = nf * 16 + (l & 15);
    float w = (k < C) ? wl[k * C + n] : wr[(k - C) * C + n];
    unsigned short h = bfbits(w);
    Wh[t] = (short)h;
    Wl[t] = (short)bfbits(w - bf2f(h));
}

// ---------- pack composed W2 (K=256,N=256) from wcomp ----------
__global__ void pack_w2_kernel(const float* __restrict__ wcomp,
                               short* __restrict__ Wh, short* __restrict__ Wl) {
    int t = blockIdx.x * 256 + threadIdx.x;
    int j = t & 7, l = (t >> 3) & 63;
    int kf = (t >> 9) & 7;
    int nf = t >> 12;
    int k = kf * 32 + ((l >> 4) << 3) + j;
    int n = nf * 16 + (l & 15);
    int sel = (k >= C ? 1 : 0) + (n >= C ? 2 : 0);
    float w = wcomp[sel * C * C + (k & (C - 1)) * C + (n & (C - 1))];
    unsigned short h = bfbits(w);
    Wh[t] = (short)h;
    Wl[t] = (short)bfbits(w - bf2f(h));
}

// ---------- fused bucket aggregate + MFMA transform ----------
// One block per bucket of 128 dst nodes. Phase A: accumulate neighbor mean
// tile in LDS (swizzled idx = r*128 + (c ^ ((r&7)<<3))). Wave w owns channels
// [w*32, w*32+32); lanes 0-31 handle edge e, 32-63 edge e+1. Phase B:
// normalize by deg. Phase C: MFMA transform, A0 = LDS mean, A1 = global rows.
template<int NF, int RELU>
__global__ __launch_bounds__(256, 2) void fused_layer_kernel(
        const float* __restrict__ X,
        const unsigned* __restrict__ elist, const int* __restrict__ gstart,
        const int* __restrict__ deg,
        const short* __restrict__ Bh, const short* __restrict__ Bl,
        const float* __restrict__ bias,
        float* O0, float* O1) {
    __shared__ float acc_s[128 * 128];   // 64 KB
    constexpr int KF = 8;
    int tid = threadIdx.x;
    int w = tid >> 6, l = tid & 63;
    int b = blockIdx.x;

    // zero LDS
    f32x4 z = (f32x4){0.f, 0.f, 0.f, 0.f};
    for (int i = tid; i < 4096; i += 256) ((f32x4*)acc_s)[i] = z;
    __syncthreads();

    // phase A: edge aggregation
    int estart = gstart[b], eend = gstart[b + 1];
    int ch = w * 32 + (l & 31);
    int esel = l >> 5;
    for (int e0 = estart; e0 < eend; e0 += 16) {
        unsigned p[8];
#pragma unroll
        for (int u = 0; u < 8; ++u) {
            int e = e0 + 2 * u + esel;
            p[u] = (e < eend) ? elist[e] : 0xFFFFFFFFu;
        }
        float v[8]; int dl[8];
#pragma unroll
        for (int u = 0; u < 8; ++u) {
            dl[u] = (p[u] >> 17) & 127;
            int s = p[u] & 0x1FFFF;
            if (s >= NN) s = 0;
            float vv = X[(size_t)s * C + ch];
            v[u] = (p[u] != 0xFFFFFFFFu) ? vv : 0.0f;
        }
#pragma unroll
        for (int u = 0; u < 8; ++u) {
            atomicAdd(&acc_s[dl[u] * 128 + (ch ^ ((dl[u] & 7) << 3))], v[u]);
        }
    }
    __syncthreads();

    // phase B: normalize by degree
    {
        int r = tid >> 1, hf = tid & 1;
        int gr = b * 128 + r;
        int d = (gr < NN) ? deg[gr] : 1;
        float inv = 1.0f / fmaxf((float)d, 1.0f);
#pragma unroll
        for (int j = 0; j < 16; ++j) {
            int idx = r * 128 + hf * 64 + j * 4;
            f32x4 t = *(f32x4*)&acc_s[idx];
            t.x *= inv; t.y *= inv; t.z *= inv; t.w *= inv;
            *(f32x4*)&acc_s[idx] = t;
        }
    }
    __syncthreads();

    // phase C: MFMA transform
    int m0 = b * 128 + w * 32;
    int lr = l & 15;
    int lk = (l >> 4) * 8;

    f32x4 acc[2][NF];
#pragma unroll
    for (int ms = 0; ms < 2; ++ms)
#pragma unroll
        for (int nf = 0; nf < NF; ++nf)
            acc[ms][nf] = (f32x4){0.f, 0.f, 0.f, 0.f};

    const bf16x8* Bhp = (const bf16x8*)Bh;
    const bf16x8* Blp = (const bf16x8*)Bl;

#pragma unroll
    for (int kf = 0; kf < KF; ++kf) {
        int kofs = (kf & 3) * 32 + lk;
        bf16x8 ah[2], al[2];
#pragma unroll
        for (int ms = 0; ms < 2; ++ms) {
            if (kf < 4) {
                int rl = w * 32 + ms * 16 + lr;
                const float* pa = &acc_s[rl * 128 + (kofs ^ ((rl & 7) << 3))];
                split8(pa, ah[ms], al[ms]);
            } else {
                int r = m0 + ms * 16 + lr;
                r = (r < NN) ? r : (NN - 1);
                split8(X + (size_t)r * C + kofs, ah[ms], al[ms]);
            }
        }
#pragma unroll
        for (int nf = 0; nf < NF; ++nf) {
            bf16x8 bh = Bhp[(nf * KF + kf) * 64 + l];
            bf16x8 bl = Blp[(nf * KF + kf) * 64 + l];
#pragma unroll
            for (int ms = 0; ms < 2; ++ms) {
                acc[ms][nf] = __builtin_amdgcn_mfma_f32_16x16x32_bf16(ah[ms], bh, acc[ms][nf], 0, 0, 0);
                acc[ms][nf] = __builtin_amdgcn_mfma_f32_16x16x32_bf16(al[ms], bh, acc[ms][nf], 0, 0, 0);
                acc[ms][nf] = __builtin_amdgcn_mfma_f32_16x16x32_bf16(ah[ms], bl, acc[ms][nf], 0, 0, 0);
            }
        }
    }

#pragma unroll
    for (int nf = 0; nf < NF; ++nf) {
        int col = nf * 16 + lr;
        float bv = bias[col];
        float* O = (NF == 8) ? O0 : ((nf < 8) ? O0 : O1);
        int c = (nf & 7) * 16 + lr;
#pragma unroll
        for (int ms = 0; ms < 2; ++ms) {
#pragma unroll
            for (int i = 0; i < 4; ++i) {
                int r = m0 + ms * 16 + (l >> 4) * 4 + i;
                if (r < NN) {
                    float v = acc[ms][nf][i] + bv;
                    if (RELU) v = fmaxf(v, 0.0f);
                    O[(size_t)r * C + c] = v;
                }
            }
        }
    }
}

// ---------- decode: out[p] = relu(a[u]+b[v]) . wd2 + bd2 ----------
__global__ __launch_bounds__(256) void decode_kernel(
        const float* __restrict__ a, const float* __restrict__ b,
        const int* __restrict__ pu, const int* __restrict__ pv,
        const float* __restrict__ wd2, const float* __restrict__ bd2,
        float* __restrict__ out) {
    int gid = blockIdx.x * 256 + threadIdx.x;
    int hw = gid >> 5;
    int lane = threadIdx.x & 31;
    int nhw = (gridDim.x * 256) >> 5;
    float4 w2 = *(const float4*)&wd2[lane * 4];
    float bout = bd2[0];
    for (int p = hw; p < NP; p += nhw) {
        int u = pu[p], v = pv[p];
        float4 av = *(const float4*)(a + (size_t)u * C + lane * 4);
        float4 bv = *(const float4*)(b + (size_t)v * C + lane * 4);
        float s = fmaxf(av.x + bv.x, 0.0f) * w2.x + fmaxf(av.y + bv.y, 0.0f) * w2.y
                + fmaxf(av.z + bv.z, 0.0f) * w2.z + fmaxf(av.w + bv.w, 0.0f) * w2.w;
#pragma unroll
        for (int off = 16; off; off >>= 1) s += __shfl_down(s, off, 32);
        if (lane == 0) out[p] = s + bout;
    }
}

extern "C" void kernel_launch(void* const* d_in, const int* in_sizes, int n_in,
                              void* d_out, int out_size, void* d_ws, size_t ws_size,
                              hipStream_t stream) {
    const float* x    = (const float*)d_in[0];
    const float* w1_l = (const float*)d_in[1];
    const float* b1   = (const float*)d_in[2];
    const float* w1_r = (const float*)d_in[3];
    const float* w2_l = (const float*)d_in[4];
    const float* b2   = (const float*)d_in[5];
    const float* w2_r = (const float*)d_in[6];
    const float* wd1  = (const float*)d_in[7];
    const float* bd1  = (const float*)d_in[8];
    const float* wd2  = (const float*)d_in[9];
    const float* bd2  = (const float*)d_in[10];
    const int* edge_index = (const int*)d_in[11];
    const int* edge_pairs = (const int*)d_in[12];

    const int* esrc = edge_index;
    const int* edst = edge_index + NE;
    const int* pu = edge_pairs;
    const int* pv = edge_pairs + NP;

    // ws: deg | gcnt | gstart | gcursor | elist | h1 | abuf | bbuf | wcomp | bcomp | packs
    int* deg     = (int*)d_ws;
    int* gcnt    = deg + ((NN + 255) & ~255);
    int* gstart  = gcnt + 1024;
    int* gcursor = gstart + 1024;
    unsigned* elist = (unsigned*)(gcursor + 1024);
    float* h1   = (float*)(elist + ((NE + 255) & ~255));
    float* abuf = h1 + (size_t)NN * C;
    float* bbuf = abuf + (size_t)NN * C;
    float* wcomp = bbuf + (size_t)NN * C;
    float* bcomp = wcomp + 4 * C * C;
    short* w1h = (short*)(bcomp + 2 * C);
    short* w1l = w1h + 256 * 128;
    short* w2h = w1l + 256 * 128;
    short* w2l = w2h + 256 * 256;

    hipMemsetAsync(deg, 0, sizeof(int) * NN, stream);
    hipMemsetAsync(gcnt, 0, sizeof(int) * 1024, stream);

    bin_count_kernel<<<(NE + 8191) / 8192, 256, 0, stream>>>(edst, gcnt, deg, NE);
    bin_scan_kernel<<<1, 1024, 0, stream>>>(gcnt, gstart, gcursor);
    bin_scatter_kernel<<<(NE + 4095) / 4096, 256, 0, stream>>>(esrc, edst, gcursor, elist, NE);

    compose_kernel<<<C + 1, C, 0, stream>>>(w2_l, w2_r, b2, wd1, bd1, wcomp, bcomp);
    pack_w1_kernel<<<128, 256, 0, stream>>>(w1_l, w1_r, w1h, w1l);
    pack_w2_kernel<<<256, 256, 0, stream>>>(wcomp, w2h, w2l);

    fused_layer_kernel<8, 1><<<NBUCK, 256, 0, stream>>>(
        x, elist, gstart, deg, w1h, w1l, b1, h1, nullptr);
    fused_layer_kernel<16, 0><<<NBUCK, 256, 0, stream>>>(
        h1, elist, gstart, deg, w2h, w2l, bcomp, abuf, bbuf);

    decode_kernel<<<4096, 256, 0, stream>>>(abuf, bbuf, pu, pv, wd2, bd2, (float*)d_out);
}

// Round 8
// 534.440 us; speedup vs baseline: 5.4543x; 5.4543x over previous
//
#include <hip/hip_runtime.h>
#include <hip/hip_bf16.h>

#define NN 100000
#define NE 1600000
#define NP 500000
#define C 128
#define NBUCK 782              // buckets of 128 dst nodes: 782*128 = 100096 >= NN

typedef __attribute__((ext_vector_type(8))) short bf16x8;
typedef __attribute__((ext_vector_type(4))) float f32x4;

__device__ inline unsigned short bfbits(float x) {
    __hip_bfloat16 h = __float2bfloat16(x);
    union { __hip_bfloat16 h; unsigned short u; } v; v.h = h;
    return v.u;
}
__device__ inline float bf2f(unsigned short b) {
    return __uint_as_float(((unsigned)b) << 16);
}

// split 8 consecutive f32 into bf16 hi + bf16 lo fragments
__device__ inline void split8(const float* p, bf16x8& hi, bf16x8& lo) {
    union { unsigned short s[8]; bf16x8 v; } uh, ul;
    f32x4 a = *(const f32x4*)p;
    f32x4 b = *(const f32x4*)(p + 4);
    float xs[8] = {a.x, a.y, a.z, a.w, b.x, b.y, b.z, b.w};
#pragma unroll
    for (int j = 0; j < 8; ++j) {
        unsigned short h = bfbits(xs[j]);
        uh.s[j] = h;
        ul.s[j] = bfbits(xs[j] - bf2f(h));
    }
    hi = uh.v;
    lo = ul.v;
}

// ---------- bucket histogram (LDS-staged) ----------
__global__ __launch_bounds__(256) void bin_count_kernel(
        const int* __restrict__ dst, int* __restrict__ gcnt, int nE) {
    __shared__ int h[NBUCK];
    int tid = threadIdx.x;
    for (int i = tid; i < NBUCK; i += 256) h[i] = 0;
    __syncthreads();
    int base = blockIdx.x * 8192;
#pragma unroll
    for (int j = 0; j < 32; ++j) {
        int e = base + tid + j * 256;
        if (e < nE) atomicAdd(&h[dst[e] >> 7], 1);
    }
    __syncthreads();
    for (int i = tid; i < NBUCK; i += 256)
        if (h[i]) atomicAdd(&gcnt[i], h[i]);
}

// ---------- scan bucket counts (one block) ----------
__global__ __launch_bounds__(1024) void bin_scan_kernel(
        const int* __restrict__ gcnt, int* __restrict__ gstart,
        int* __restrict__ gcursor) {
    __shared__ int s[1024];
    int tid = threadIdx.x;
    int v = (tid < NBUCK) ? gcnt[tid] : 0;
    s[tid] = v;
    __syncthreads();
    for (int off = 1; off < 1024; off <<= 1) {
        int t = (tid >= off) ? s[tid - off] : 0;
        __syncthreads();
        s[tid] += t;
        __syncthreads();
    }
    int excl = s[tid] - v;
    if (tid < NBUCK) { gstart[tid] = excl; gcursor[tid] = excl; }
    if (tid == NBUCK - 1) gstart[NBUCK] = excl + v;
}

// ---------- LDS-staged multisplit scatter: coalesced bucket-grouped writes ----------
__global__ __launch_bounds__(256) void bin_scatter_kernel(
        const int* __restrict__ src, const int* __restrict__ dst,
        int* __restrict__ gcursor, unsigned* __restrict__ elist, int nE) {
    __shared__ unsigned stage[4096];
    __shared__ unsigned short sbkt[4096];
    __shared__ int h[NBUCK];
    __shared__ int ex[NBUCK];
    __shared__ int gb[NBUCK];
    __shared__ int psum[256];
    int tid = threadIdx.x;
    for (int i = tid; i < NBUCK; i += 256) h[i] = 0;
    __syncthreads();
    int base = blockIdx.x * 4096;
    unsigned pk[16]; int bk[16];
#pragma unroll
    for (int j = 0; j < 16; ++j) {
        int e = base + tid + j * 256;
        bool ok = e < nE;
        int d = ok ? dst[e] : 0;
        int s = ok ? src[e] : 0;
        bk[j] = ok ? (d >> 7) : -1;
        pk[j] = ((unsigned)(d & 127) << 17) | (unsigned)s;
        if (ok) atomicAdd(&h[bk[j]], 1);
    }
    __syncthreads();
    int lo = tid * 4;
    int c4[4]; int sum = 0;
#pragma unroll
    for (int j = 0; j < 4; ++j) {
        int idx = lo + j;
        c4[j] = (idx < NBUCK) ? h[idx] : 0;
        sum += c4[j];
    }
    psum[tid] = sum;
    __syncthreads();
    for (int off = 1; off < 256; off <<= 1) {
        int t = (tid >= off) ? psum[tid - off] : 0;
        __syncthreads();
        psum[tid] += t;
        __syncthreads();
    }
    int run = psum[tid] - sum;
#pragma unroll
    for (int j = 0; j < 4; ++j) {
        int idx = lo + j;
        if (idx < NBUCK) ex[idx] = run;
        run += c4[j];
    }
    __syncthreads();
    for (int i = tid; i < NBUCK; i += 256)
        if (h[i] > 0) gb[i] = atomicAdd(&gcursor[i], h[i]);
    for (int i = tid; i < NBUCK; i += 256) h[i] = 0;
    __syncthreads();
#pragma unroll
    for (int j = 0; j < 16; ++j) {
        if (bk[j] >= 0) {
            int r = ex[bk[j]] + atomicAdd(&h[bk[j]], 1);
            stage[r] = pk[j];
            sbkt[r] = (unsigned short)bk[j];
        }
    }
    __syncthreads();
    int tot = min(4096, nE - base);
    for (int i = tid; i < tot; i += 256) {
        int b = sbkt[i];
        elist[gb[b] + (i - ex[b])] = stage[i];
    }
}

// ---------- per-bucket counting sort -> exact per-node CSR + offs ----------
// One block per bucket. Writes land in the bucket's own CSR window (~8 KB)
// so write amplification ~1. Also emits offs (exclusive starts), coalesced.
__global__ __launch_bounds__(256) void bucket_csr_kernel(
        const unsigned* __restrict__ elist, const int* __restrict__ gstart,
        int* __restrict__ ssrc, int* __restrict__ offs) {
    __shared__ int cnt[128];
    __shared__ int sc[128];
    int tid = threadIdx.x;
    int b = blockIdx.x;
    if (tid < 128) cnt[tid] = 0;
    __syncthreads();
    int s = gstart[b], e = gstart[b + 1];
    for (int i = s + tid; i < e; i += 256)
        atomicAdd(&cnt[(elist[i] >> 17) & 127], 1);
    __syncthreads();
    int v = 0;
    if (tid < 128) { v = cnt[tid]; sc[tid] = v; }
    __syncthreads();
    for (int off = 1; off < 128; off <<= 1) {
        int t = 0;
        if (tid < 128 && tid >= off) t = sc[tid - off];
        __syncthreads();
        if (tid < 128) sc[tid] += t;
        __syncthreads();
    }
    if (tid < 128) {
        int start = s + sc[tid] - v;
        cnt[tid] = start;                   // reuse cnt as global cursor
        int node = b * 128 + tid;
        if (node < NN) offs[node] = start;
    }
    if (b == NBUCK - 1 && tid == 0) offs[NN] = NE;
    __syncthreads();
    for (int i = s + tid; i < e; i += 256) {
        unsigned p = elist[i];
        int r = (p >> 17) & 127;
        int pos = atomicAdd(&cnt[r], 1);
        ssrc[pos] = (int)(p & 0x1FFFF);
    }
}

// ---------- compose decode projection into layer-2 weights ----------
__global__ void compose_kernel(const float* __restrict__ w2l, const float* __restrict__ w2r,
                               const float* __restrict__ b2,
                               const float* __restrict__ wd1, const float* __restrict__ bd1,
                               float* __restrict__ wcomp, float* __restrict__ bcomp) {
    int c = threadIdx.x;
    int k = blockIdx.x;
    if (k < C) {
        float wma = 0, wmb = 0, wha = 0, whb = 0;
        for (int j = 0; j < C; ++j) {
            float wt = wd1[j * C + c];
            float wb = wd1[(C + j) * C + c];
            float l = w2l[k * C + j];
            float r = w2r[k * C + j];
            wma += l * wt; wmb += l * wb;
            wha += r * wt; whb += r * wb;
        }
        wcomp[0 * C * C + k * C + c] = wma;
        wcomp[1 * C * C + k * C + c] = wha;
        wcomp[2 * C * C + k * C + c] = wmb;
        wcomp[3 * C * C + k * C + c] = whb;
    } else {
        float ba = bd1[c], bb = 0;
        for (int j = 0; j < C; ++j) {
            float bj = b2[j];
            ba += bj * wd1[j * C + c];
            bb += bj * wd1[(C + j) * C + c];
        }
        bcomp[c] = ba;
        bcomp[C + c] = bb;
    }
}

// ---------- pack W1=[wl;wr] (K=256,N=128) into B-fragment layout, bf16 hi/lo ----------
__global__ void pack_w1_kernel(const float* __restrict__ wl, const float* __restrict__ wr,
                               short* __restrict__ Wh, short* __restrict__ Wl) {
    int t = blockIdx.x * 256 + threadIdx.x;
    int j = t & 7, l = (t >> 3) & 63;
    int kf = (t >> 9) & 7;
    int nf = t >> 12;
    int k = kf * 32 + ((l >> 4) << 3) + j;
    int n = nf * 16 + (l & 15);
    float w = (k < C) ? wl[k * C + n] : wr[(k - C) * C + n];
    unsigned short h = bfbits(w);
    Wh[t] = (short)h;
    Wl[t] = (short)bfbits(w - bf2f(h));
}

// ---------- pack composed W2 (K=256,N=256) from wcomp ----------
__global__ void pack_w2_kernel(const float* __restrict__ wcomp,
                               short* __restrict__ Wh, short* __restrict__ Wl) {
    int t = blockIdx.x * 256 + threadIdx.x;
    int j = t & 7, l = (t >> 3) & 63;
    int kf = (t >> 9) & 7;
    int nf = t >> 12;
    int k = kf * 32 + ((l >> 4) << 3) + j;
    int n = nf * 16 + (l & 15);
    int sel = (k >= C ? 1 : 0) + (n >= C ? 2 : 0);
    float w = wcomp[sel * C * C + (k & (C - 1)) * C + (n & (C - 1))];
    unsigned short h = bfbits(w);
    Wh[t] = (short)h;
    Wl[t] = (short)bfbits(w - bf2f(h));
}

// ---------- gather mean: half-wave (32 lanes x float4) per node ----------
__global__ __launch_bounds__(256) void gather_mean_kernel(
        const float* __restrict__ xin, const int* __restrict__ offs,
        const int* __restrict__ ssrc, float* __restrict__ mean) {
    int gid = blockIdx.x * 256 + threadIdx.x;
    int hw = gid >> 5;
    int lane = threadIdx.x & 31;
    int nhw = (gridDim.x * 256) >> 5;
    for (int n = hw; n < NN; n += nhw) {
        int start = offs[n];
        int end = offs[n + 1];
        float4 acc = make_float4(0.f, 0.f, 0.f, 0.f);
        int e = start;
        for (; e + 3 < end; e += 4) {
            int s0 = ssrc[e], s1 = ssrc[e + 1], s2 = ssrc[e + 2], s3 = ssrc[e + 3];
            float4 v0 = *(const float4*)(xin + (size_t)s0 * C + lane * 4);
            float4 v1 = *(const float4*)(xin + (size_t)s1 * C + lane * 4);
            float4 v2 = *(const float4*)(xin + (size_t)s2 * C + lane * 4);
            float4 v3 = *(const float4*)(xin + (size_t)s3 * C + lane * 4);
            acc.x += v0.x + v1.x + v2.x + v3.x;
            acc.y += v0.y + v1.y + v2.y + v3.y;
            acc.z += v0.z + v1.z + v2.z + v3.z;
            acc.w += v0.w + v1.w + v2.w + v3.w;
        }
        for (; e < end; ++e) {
            float4 v = *(const float4*)(xin + (size_t)ssrc[e] * C + lane * 4);
            acc.x += v.x; acc.y += v.y; acc.z += v.z; acc.w += v.w;
        }
        float inv = 1.0f / fmaxf((float)(end - start), 1.0f);
        acc.x *= inv; acc.y *= inv; acc.z *= inv; acc.w *= inv;
        *(float4*)(mean + (size_t)n * C + lane * 4) = acc;
    }
}

// ---------- MFMA transform: Y[NN x NF*16] = [A0|A1][NN x 256] @ W + bias ----------
template<int NF, int RELU>
__global__ __launch_bounds__(256, 2) void mfma_transform_kernel(
        const float* A0, const float* A1,
        const short* __restrict__ Bh, const short* __restrict__ Bl,
        const float* __restrict__ bias,
        float* O0, float* O1) {
    constexpr int KF = 8;
    int tid = threadIdx.x;
    int w = tid >> 6, l = tid & 63;
    int m0 = blockIdx.x * 128 + w * 32;
    int lr = l & 15;
    int lk = (l >> 4) * 8;

    f32x4 acc[2][NF];
#pragma unroll
    for (int ms = 0; ms < 2; ++ms)
#pragma unroll
        for (int nf = 0; nf < NF; ++nf)
            acc[ms][nf] = (f32x4){0.0f, 0.0f, 0.0f, 0.0f};

    const bf16x8* Bhp = (const bf16x8*)Bh;
    const bf16x8* Blp = (const bf16x8*)Bl;

#pragma unroll
    for (int kf = 0; kf < KF; ++kf) {
        const float* Asrc = (kf < 4) ? A0 : A1;
        int kofs = (kf & 3) * 32 + lk;
        bf16x8 ah[2], al[2];
#pragma unroll
        for (int ms = 0; ms < 2; ++ms) {
            int r = m0 + ms * 16 + lr;
            r = (r < NN) ? r : (NN - 1);
            split8(Asrc + (size_t)r * C + kofs, ah[ms], al[ms]);
        }
#pragma unroll
        for (int nf = 0; nf < NF; ++nf) {
            bf16x8 bh = Bhp[(nf * KF + kf) * 64 + l];
            bf16x8 bl = Blp[(nf * KF + kf) * 64 + l];
#pragma unroll
            for (int ms = 0; ms < 2; ++ms) {
                acc[ms][nf] = __builtin_amdgcn_mfma_f32_16x16x32_bf16(ah[ms], bh, acc[ms][nf], 0, 0, 0);
                acc[ms][nf] = __builtin_amdgcn_mfma_f32_16x16x32_bf16(al[ms], bh, acc[ms][nf], 0, 0, 0);
                acc[ms][nf] = __builtin_amdgcn_mfma_f32_16x16x32_bf16(ah[ms], bl, acc[ms][nf], 0, 0, 0);
            }
        }
    }

#pragma unroll
    for (int nf = 0; nf < NF; ++nf) {
        int col = nf * 16 + lr;
        float bv = bias[col];
        float* O = (NF == 8) ? O0 : ((nf < 8) ? O0 : O1);
        int c = (nf & 7) * 16 + lr;
#pragma unroll
        for (int ms = 0; ms < 2; ++ms) {
#pragma unroll
            for (int i = 0; i < 4; ++i) {
                int r = m0 + ms * 16 + (l >> 4) * 4 + i;
                if (r < NN) {
                    float v = acc[ms][nf][i] + bv;
                    if (RELU) v = fmaxf(v, 0.0f);
                    O[(size_t)r * C + c] = v;
                }
            }
        }
    }
}

// ---------- decode: out[p] = relu(a[u]+b[v]) . wd2 + bd2 ----------
__global__ __launch_bounds__(256) void decode_kernel(
        const float* __restrict__ a, const float* __restrict__ b,
        const int* __restrict__ pu, const int* __restrict__ pv,
        const float* __restrict__ wd2, const float* __restrict__ bd2,
        float* __restrict__ out) {
    int gid = blockIdx.x * 256 + threadIdx.x;
    int hw = gid >> 5;
    int lane = threadIdx.x & 31;
    int nhw = (gridDim.x * 256) >> 5;
    float4 w2 = *(const float4*)&wd2[lane * 4];
    float bout = bd2[0];
    for (int p = hw; p < NP; p += nhw) {
        int u = pu[p], v = pv[p];
        float4 av = *(const float4*)(a + (size_t)u * C + lane * 4);
        float4 bv = *(const float4*)(b + (size_t)v * C + lane * 4);
        float s = fmaxf(av.x + bv.x, 0.0f) * w2.x + fmaxf(av.y + bv.y, 0.0f) * w2.y
                + fmaxf(av.z + bv.z, 0.0f) * w2.z + fmaxf(av.w + bv.w, 0.0f) * w2.w;
#pragma unroll
        for (int off = 16; off; off >>= 1) s += __shfl_down(s, off, 32);
        if (lane == 0) out[p] = s + bout;
    }
}

extern "C" void kernel_launch(void* const* d_in, const int* in_sizes, int n_in,
                              void* d_out, int out_size, void* d_ws, size_t ws_size,
                              hipStream_t stream) {
    const float* x    = (const float*)d_in[0];
    const float* w1_l = (const float*)d_in[1];
    const float* b1   = (const float*)d_in[2];
    const float* w1_r = (const float*)d_in[3];
    const float* w2_l = (const float*)d_in[4];
    const float* b2   = (const float*)d_in[5];
    const float* w2_r = (const float*)d_in[6];
    const float* wd1  = (const float*)d_in[7];
    const float* bd1  = (const float*)d_in[8];
    const float* wd2  = (const float*)d_in[9];
    const float* bd2  = (const float*)d_in[10];
    const int* edge_index = (const int*)d_in[11];
    const int* edge_pairs = (const int*)d_in[12];

    const int* esrc = edge_index;
    const int* edst = edge_index + NE;
    const int* pu = edge_pairs;
    const int* pv = edge_pairs + NP;

    // ws: gcnt | gstart | gcursor | offs[NN+1 pad] | elist | ssrc | mean | h1 | wcomp | bcomp | packs
    int* gcnt    = (int*)d_ws;
    int* gstart  = gcnt + 1024;
    int* gcursor = gstart + 1024;
    int* offs    = gcursor + 1024;
    unsigned* elist = (unsigned*)(offs + ((NN + 1 + 255) & ~255));
    int* ssrc    = (int*)(elist + NE);
    float* mean  = (float*)(ssrc + ((NE + 255) & ~255));
    float* h1    = mean + (size_t)NN * C;
    float* wcomp = h1 + (size_t)NN * C;
    float* bcomp = wcomp + 4 * C * C;
    short* w1h = (short*)(bcomp + 2 * C);
    short* w1l = w1h + 256 * 128;
    short* w2h = w1l + 256 * 128;
    short* w2l = w2h + 256 * 256;

    hipMemsetAsync(gcnt, 0, sizeof(int) * 1024, stream);

    bin_count_kernel<<<(NE + 8191) / 8192, 256, 0, stream>>>(edst, gcnt, NE);
    bin_scan_kernel<<<1, 1024, 0, stream>>>(gcnt, gstart, gcursor);
    bin_scatter_kernel<<<(NE + 4095) / 4096, 256, 0, stream>>>(esrc, edst, gcursor, elist, NE);
    bucket_csr_kernel<<<NBUCK, 256, 0, stream>>>(elist, gstart, ssrc, offs);

    compose_kernel<<<C + 1, C, 0, stream>>>(w2_l, w2_r, b2, wd1, bd1, wcomp, bcomp);
    pack_w1_kernel<<<128, 256, 0, stream>>>(w1_l, w1_r, w1h, w1l);
    pack_w2_kernel<<<256, 256, 0, stream>>>(wcomp, w2h, w2l);

    int tblocks = (NN + 127) / 128;   // 782
    gather_mean_kernel<<<6144, 256, 0, stream>>>(x, offs, ssrc, mean);
    mfma_transform_kernel<8, 1><<<tblocks, 256, 0, stream>>>(
        mean, x, w1h, w1l, b1, h1, nullptr);
    gather_mean_kernel<<<6144, 256, 0, stream>>>(h1, offs, ssrc, mean);
    // outputs alias inputs: a -> mean buffer, b -> h1 buffer (safe: each wave
    // reads only its own 32 rows in the K-loop before its epilogue writes them)
    mfma_transform_kernel<16, 0><<<tblocks, 256, 0, stream>>>(
        mean, h1, w2h, w2l, bcomp, mean, h1);

    decode_kernel<<<4096, 256, 0, stream>>>(mean, h1, pu, pv, wd2, bd2, (float*)d_out);
}

// Round 9
// 518.269 us; speedup vs baseline: 5.6245x; 1.0312x over previous
//
#include <hip/hip_runtime.h>
#include <hip/hip_bf16.h>

#define NN 100000
#define NE 1600000
#define NP 500000
#define C 128
#define NBUCK 782              // buckets of 128 dst nodes: 782*128 = 100096 >= NN

typedef __attribute__((ext_vector_type(8))) short bf16x8;
typedef __attribute__((ext_vector_type(4))) float f32x4;

__device__ inline unsigned short bfbits(float x) {
    __hip_bfloat16 h = __float2bfloat16(x);
    union { __hip_bfloat16 h; unsigned short u; } v; v.h = h;
    return v.u;
}
__device__ inline float bf2f(unsigned short b) {
    return __uint_as_float(((unsigned)b) << 16);
}

// split 8 consecutive f32 into bf16 hi + bf16 lo fragments
__device__ inline void split8(const float* p, bf16x8& hi, bf16x8& lo) {
    union { unsigned short s[8]; bf16x8 v; } uh, ul;
    f32x4 a = *(const f32x4*)p;
    f32x4 b = *(const f32x4*)(p + 4);
    float xs[8] = {a.x, a.y, a.z, a.w, b.x, b.y, b.z, b.w};
#pragma unroll
    for (int j = 0; j < 8; ++j) {
        unsigned short h = bfbits(xs[j]);
        uh.s[j] = h;
        ul.s[j] = bfbits(xs[j] - bf2f(h));
    }
    hi = uh.v;
    lo = ul.v;
}

// ---------- bucket histogram (LDS-staged) ----------
__global__ __launch_bounds__(256) void bin_count_kernel(
        const int* __restrict__ dst, int* __restrict__ gcnt, int nE) {
    __shared__ int h[NBUCK];
    int tid = threadIdx.x;
    for (int i = tid; i < NBUCK; i += 256) h[i] = 0;
    __syncthreads();
    int base = blockIdx.x * 8192;
#pragma unroll
    for (int j = 0; j < 32; ++j) {
        int e = base + tid + j * 256;
        if (e < nE) atomicAdd(&h[dst[e] >> 7], 1);
    }
    __syncthreads();
    for (int i = tid; i < NBUCK; i += 256)
        if (h[i]) atomicAdd(&gcnt[i], h[i]);
}

// ---------- scan bucket counts (one block) ----------
__global__ __launch_bounds__(1024) void bin_scan_kernel(
        const int* __restrict__ gcnt, int* __restrict__ gstart,
        int* __restrict__ gcursor) {
    __shared__ int s[1024];
    int tid = threadIdx.x;
    int v = (tid < NBUCK) ? gcnt[tid] : 0;
    s[tid] = v;
    __syncthreads();
    for (int off = 1; off < 1024; off <<= 1) {
        int t = (tid >= off) ? s[tid - off] : 0;
        __syncthreads();
        s[tid] += t;
        __syncthreads();
    }
    int excl = s[tid] - v;
    if (tid < NBUCK) { gstart[tid] = excl; gcursor[tid] = excl; }
    if (tid == NBUCK - 1) gstart[NBUCK] = excl + v;
}

// ---------- LDS-staged multisplit scatter: coalesced bucket-grouped writes ----------
__global__ __launch_bounds__(256) void bin_scatter_kernel(
        const int* __restrict__ src, const int* __restrict__ dst,
        int* __restrict__ gcursor, unsigned* __restrict__ elist, int nE) {
    __shared__ unsigned stage[4096];
    __shared__ unsigned short sbkt[4096];
    __shared__ int h[NBUCK];
    __shared__ int ex[NBUCK];
    __shared__ int gb[NBUCK];
    __shared__ int psum[256];
    int tid = threadIdx.x;
    for (int i = tid; i < NBUCK; i += 256) h[i] = 0;
    __syncthreads();
    int base = blockIdx.x * 4096;
    unsigned pk[16]; int bk[16];
#pragma unroll
    for (int j = 0; j < 16; ++j) {
        int e = base + tid + j * 256;
        bool ok = e < nE;
        int d = ok ? dst[e] : 0;
        int s = ok ? src[e] : 0;
        bk[j] = ok ? (d >> 7) : -1;
        pk[j] = ((unsigned)(d & 127) << 17) | (unsigned)s;
        if (ok) atomicAdd(&h[bk[j]], 1);
    }
    __syncthreads();
    int lo = tid * 4;
    int c4[4]; int sum = 0;
#pragma unroll
    for (int j = 0; j < 4; ++j) {
        int idx = lo + j;
        c4[j] = (idx < NBUCK) ? h[idx] : 0;
        sum += c4[j];
    }
    psum[tid] = sum;
    __syncthreads();
    for (int off = 1; off < 256; off <<= 1) {
        int t = (tid >= off) ? psum[tid - off] : 0;
        __syncthreads();
        psum[tid] += t;
        __syncthreads();
    }
    int run = psum[tid] - sum;
#pragma unroll
    for (int j = 0; j < 4; ++j) {
        int idx = lo + j;
        if (idx < NBUCK) ex[idx] = run;
        run += c4[j];
    }
    __syncthreads();
    for (int i = tid; i < NBUCK; i += 256)
        if (h[i] > 0) gb[i] = atomicAdd(&gcursor[i], h[i]);
    for (int i = tid; i < NBUCK; i += 256) h[i] = 0;
    __syncthreads();
#pragma unroll
    for (int j = 0; j < 16; ++j) {
        if (bk[j] >= 0) {
            int r = ex[bk[j]] + atomicAdd(&h[bk[j]], 1);
            stage[r] = pk[j];
            sbkt[r] = (unsigned short)bk[j];
        }
    }
    __syncthreads();
    int tot = min(4096, nE - base);
    for (int i = tid; i < tot; i += 256) {
        int b = sbkt[i];
        elist[gb[b] + (i - ex[b])] = stage[i];
    }
}

// ---------- per-bucket counting sort -> exact per-node CSR + offs ----------
__global__ __launch_bounds__(256) void bucket_csr_kernel(
        const unsigned* __restrict__ elist, const int* __restrict__ gstart,
        int* __restrict__ ssrc, int* __restrict__ offs) {
    __shared__ int cnt[128];
    __shared__ int sc[128];
    int tid = threadIdx.x;
    int b = blockIdx.x;
    if (tid < 128) cnt[tid] = 0;
    __syncthreads();
    int s = gstart[b], e = gstart[b + 1];
    for (int i = s + tid; i < e; i += 256)
        atomicAdd(&cnt[(elist[i] >> 17) & 127], 1);
    __syncthreads();
    int v = 0;
    if (tid < 128) { v = cnt[tid]; sc[tid] = v; }
    __syncthreads();
    for (int off = 1; off < 128; off <<= 1) {
        int t = 0;
        if (tid < 128 && tid >= off) t = sc[tid - off];
        __syncthreads();
        if (tid < 128) sc[tid] += t;
        __syncthreads();
    }
    if (tid < 128) {
        int start = s + sc[tid] - v;
        cnt[tid] = start;
        int node = b * 128 + tid;
        if (node < NN) offs[node] = start;
    }
    if (b == NBUCK - 1 && tid == 0) offs[NN] = NE;
    __syncthreads();
    for (int i = s + tid; i < e; i += 256) {
        unsigned p = elist[i];
        int r = (p >> 17) & 127;
        int pos = atomicAdd(&cnt[r], 1);
        ssrc[pos] = (int)(p & 0x1FFFF);
    }
}

// ---------- compose decode projection into layer-2 weights ----------
__global__ void compose_kernel(const float* __restrict__ w2l, const float* __restrict__ w2r,
                               const float* __restrict__ b2,
                               const float* __restrict__ wd1, const float* __restrict__ bd1,
                               float* __restrict__ wcomp, float* __restrict__ bcomp) {
    int c = threadIdx.x;
    int k = blockIdx.x;
    if (k < C) {
        float wma = 0, wmb = 0, wha = 0, whb = 0;
        for (int j = 0; j < C; ++j) {
            float wt = wd1[j * C + c];
            float wb = wd1[(C + j) * C + c];
            float l = w2l[k * C + j];
            float r = w2r[k * C + j];
            wma += l * wt; wmb += l * wb;
            wha += r * wt; whb += r * wb;
        }
        wcomp[0 * C * C + k * C + c] = wma;
        wcomp[1 * C * C + k * C + c] = wha;
        wcomp[2 * C * C + k * C + c] = wmb;
        wcomp[3 * C * C + k * C + c] = whb;
    } else {
        float ba = bd1[c], bb = 0;
        for (int j = 0; j < C; ++j) {
            float bj = b2[j];
            ba += bj * wd1[j * C + c];
            bb += bj * wd1[(C + j) * C + c];
        }
        bcomp[c] = ba;
        bcomp[C + c] = bb;
    }
}

// ---------- pack W1=[wl;wr] (K=256,N=128) into B-fragment layout, bf16 hi/lo ----------
__global__ void pack_w1_kernel(const float* __restrict__ wl, const float* __restrict__ wr,
                               short* __restrict__ Wh, short* __restrict__ Wl) {
    int t = blockIdx.x * 256 + threadIdx.x;
    int j = t & 7, l = (t >> 3) & 63;
    int kf = (t >> 9) & 7;
    int nf = t >> 12;
    int k = kf * 32 + ((l >> 4) << 3) + j;
    int n = nf * 16 + (l & 15);
    float w = (k < C) ? wl[k * C + n] : wr[(k - C) * C + n];
    unsigned short h = bfbits(w);
    Wh[t] = (short)h;
    Wl[t] = (short)bfbits(w - bf2f(h));
}

// ---------- pack composed W2 (K=256,N=256) from wcomp ----------
__global__ void pack_w2_kernel(const float* __restrict__ wcomp,
                               short* __restrict__ Wh, short* __restrict__ Wl) {
    int t = blockIdx.x * 256 + threadIdx.x;
    int j = t & 7, l = (t >> 3) & 63;
    int kf = (t >> 9) & 7;
    int nf = t >> 12;
    int k = kf * 32 + ((l >> 4) << 3) + j;
    int n = nf * 16 + (l & 15);
    int sel = (k >= C ? 1 : 0) + (n >= C ? 2 : 0);
    float w = wcomp[sel * C * C + (k & (C - 1)) * C + (n & (C - 1))];
    unsigned short h = bfbits(w);
    Wh[t] = (short)h;
    Wl[t] = (short)bfbits(w - bf2f(h));
}

// ---------- gather mean: half-wave (32 lanes x float4) per node ----------
__global__ __launch_bounds__(256) void gather_mean_kernel(
        const float* __restrict__ xin, const int* __restrict__ offs,
        const int* __restrict__ ssrc, float* __restrict__ mean) {
    int gid = blockIdx.x * 256 + threadIdx.x;
    int hw = gid >> 5;
    int lane = threadIdx.x & 31;
    int nhw = (gridDim.x * 256) >> 5;
    for (int n = hw; n < NN; n += nhw) {
        int start = offs[n];
        int end = offs[n + 1];
        float4 acc = make_float4(0.f, 0.f, 0.f, 0.f);
        int e = start;
        for (; e + 3 < end; e += 4) {
            int s0 = ssrc[e], s1 = ssrc[e + 1], s2 = ssrc[e + 2], s3 = ssrc[e + 3];
            float4 v0 = *(const float4*)(xin + (size_t)s0 * C + lane * 4);
            float4 v1 = *(const float4*)(xin + (size_t)s1 * C + lane * 4);
            float4 v2 = *(const float4*)(xin + (size_t)s2 * C + lane * 4);
            float4 v3 = *(const float4*)(xin + (size_t)s3 * C + lane * 4);
            acc.x += v0.x + v1.x + v2.x + v3.x;
            acc.y += v0.y + v1.y + v2.y + v3.y;
            acc.z += v0.z + v1.z + v2.z + v3.z;
            acc.w += v0.w + v1.w + v2.w + v3.w;
        }
        for (; e < end; ++e) {
            float4 v = *(const float4*)(xin + (size_t)ssrc[e] * C + lane * 4);
            acc.x += v.x; acc.y += v.y; acc.z += v.z; acc.w += v.w;
        }
        float inv = 1.0f / fmaxf((float)(end - start), 1.0f);
        acc.x *= inv; acc.y *= inv; acc.z *= inv; acc.w *= inv;
        *(float4*)(mean + (size_t)n * C + lane * 4) = acc;
    }
}

// ---------- MFMA transform: Y[NN x NF*16] = [A0|A1][NN x 256] @ W + bias ----------
// MS = 16-row fragments per wave. Block covers 64*MS rows. acc = MS*NF*4 VGPR;
// kept <=64 so 4 waves/SIMD fit (launch_bounds(256,4)) to hide B-load latency.
template<int MS, int NF, int RELU>
__global__ __launch_bounds__(256, 4) void mfma_transform_kernel(
        const float* A0, const float* A1,
        const short* __restrict__ Bh, const short* __restrict__ Bl,
        const float* __restrict__ bias,
        float* O0, float* O1) {
    constexpr int KF = 8;
    int tid = threadIdx.x;
    int w = tid >> 6, l = tid & 63;
    int m0 = blockIdx.x * (64 * MS) + w * (MS * 16);
    int lr = l & 15;
    int lk = (l >> 4) * 8;

    f32x4 acc[MS][NF];
#pragma unroll
    for (int ms = 0; ms < MS; ++ms)
#pragma unroll
        for (int nf = 0; nf < NF; ++nf)
            acc[ms][nf] = (f32x4){0.0f, 0.0f, 0.0f, 0.0f};

    const bf16x8* Bhp = (const bf16x8*)Bh;
    const bf16x8* Blp = (const bf16x8*)Bl;

#pragma unroll
    for (int kf = 0; kf < KF; ++kf) {
        const float* Asrc = (kf < 4) ? A0 : A1;
        int kofs = (kf & 3) * 32 + lk;
        bf16x8 ah[MS], al[MS];
#pragma unroll
        for (int ms = 0; ms < MS; ++ms) {
            int r = m0 + ms * 16 + lr;
            r = (r < NN) ? r : (NN - 1);
            split8(Asrc + (size_t)r * C + kofs, ah[ms], al[ms]);
        }
#pragma unroll
        for (int nf = 0; nf < NF; ++nf) {
            bf16x8 bh = Bhp[(nf * KF + kf) * 64 + l];
            bf16x8 bl = Blp[(nf * KF + kf) * 64 + l];
#pragma unroll
            for (int ms = 0; ms < MS; ++ms) {
                acc[ms][nf] = __builtin_amdgcn_mfma_f32_16x16x32_bf16(ah[ms], bh, acc[ms][nf], 0, 0, 0);
                acc[ms][nf] = __builtin_amdgcn_mfma_f32_16x16x32_bf16(al[ms], bh, acc[ms][nf], 0, 0, 0);
                acc[ms][nf] = __builtin_amdgcn_mfma_f32_16x16x32_bf16(ah[ms], bl, acc[ms][nf], 0, 0, 0);
            }
        }
    }

#pragma unroll
    for (int nf = 0; nf < NF; ++nf) {
        int col = nf * 16 + lr;
        float bv = bias[col];
        float* O = (NF == 8) ? O0 : ((nf < 8) ? O0 : O1);
        int c = (nf & 7) * 16 + lr;
#pragma unroll
        for (int ms = 0; ms < MS; ++ms) {
#pragma unroll
            for (int i = 0; i < 4; ++i) {
                int r = m0 + ms * 16 + (l >> 4) * 4 + i;
                if (r < NN) {
                    float v = acc[ms][nf][i] + bv;
                    if (RELU) v = fmaxf(v, 0.0f);
                    O[(size_t)r * C + c] = v;
                }
            }
        }
    }
}

// ---------- decode: out[p] = relu(a[u]+b[v]) . wd2 + bd2 ----------
// half-wave (32 lanes x float4) per pair, 2 pairs in flight per half-wave.
__global__ __launch_bounds__(256) void decode_kernel(
        const float* __restrict__ a, const float* __restrict__ b,
        const int* __restrict__ pu, const int* __restrict__ pv,
        const float* __restrict__ wd2, const float* __restrict__ bd2,
        float* __restrict__ out) {
    int gid = blockIdx.x * 256 + threadIdx.x;
    int hw = gid >> 5;
    int lane = threadIdx.x & 31;
    int nhw = (gridDim.x * 256) >> 5;
    float4 w2 = *(const float4*)&wd2[lane * 4];
    float bout = bd2[0];
    for (int p = hw; p < NP; p += 2 * nhw) {
        int p2 = p + nhw;
        bool ok2 = p2 < NP;
        int u1 = pu[p], v1 = pv[p];
        int u2 = ok2 ? pu[p2] : 0, v2 = ok2 ? pv[p2] : 0;
        float4 a1 = *(const float4*)(a + (size_t)u1 * C + lane * 4);
        float4 b1 = *(const float4*)(b + (size_t)v1 * C + lane * 4);
        float4 a2 = *(const float4*)(a + (size_t)u2 * C + lane * 4);
        float4 b2 = *(const float4*)(b + (size_t)v2 * C + lane * 4);
        float s1 = fmaxf(a1.x + b1.x, 0.0f) * w2.x + fmaxf(a1.y + b1.y, 0.0f) * w2.y
                 + fmaxf(a1.z + b1.z, 0.0f) * w2.z + fmaxf(a1.w + b1.w, 0.0f) * w2.w;
        float s2 = fmaxf(a2.x + b2.x, 0.0f) * w2.x + fmaxf(a2.y + b2.y, 0.0f) * w2.y
                 + fmaxf(a2.z + b2.z, 0.0f) * w2.z + fmaxf(a2.w + b2.w, 0.0f) * w2.w;
#pragma unroll
        for (int off = 16; off; off >>= 1) {
            s1 += __shfl_down(s1, off, 32);
            s2 += __shfl_down(s2, off, 32);
        }
        if (lane == 0) {
            out[p] = s1 + bout;
            if (ok2) out[p2] = s2 + bout;
        }
    }
}

extern "C" void kernel_launch(void* const* d_in, const int* in_sizes, int n_in,
                              void* d_out, int out_size, void* d_ws, size_t ws_size,
                              hipStream_t stream) {
    const float* x    = (const float*)d_in[0];
    const float* w1_l = (const float*)d_in[1];
    const float* b1   = (const float*)d_in[2];
    const float* w1_r = (const float*)d_in[3];
    const float* w2_l = (const float*)d_in[4];
    const float* b2   = (const float*)d_in[5];
    const float* w2_r = (const float*)d_in[6];
    const float* wd1  = (const float*)d_in[7];
    const float* bd1  = (const float*)d_in[8];
    const float* wd2  = (const float*)d_in[9];
    const float* bd2  = (const float*)d_in[10];
    const int* edge_index = (const int*)d_in[11];
    const int* edge_pairs = (const int*)d_in[12];

    const int* esrc = edge_index;
    const int* edst = edge_index + NE;
    const int* pu = edge_pairs;
    const int* pv = edge_pairs + NP;

    // ws: gcnt | gstart | gcursor | offs[NN+1 pad] | elist | ssrc | mean | h1 | wcomp | bcomp | packs
    int* gcnt    = (int*)d_ws;
    int* gstart  = gcnt + 1024;
    int* gcursor = gstart + 1024;
    int* offs    = gcursor + 1024;
    unsigned* elist = (unsigned*)(offs + ((NN + 1 + 255) & ~255));
    int* ssrc    = (int*)(elist + NE);
    float* mean  = (float*)(ssrc + ((NE + 255) & ~255));
    float* h1    = mean + (size_t)NN * C;
    float* wcomp = h1 + (size_t)NN * C;
    float* bcomp = wcomp + 4 * C * C;
    short* w1h = (short*)(bcomp + 2 * C);
    short* w1l = w1h + 256 * 128;
    short* w2h = w1l + 256 * 128;
    short* w2l = w2h + 256 * 256;

    hipMemsetAsync(gcnt, 0, sizeof(int) * 1024, stream);

    bin_count_kernel<<<(NE + 8191) / 8192, 256, 0, stream>>>(edst, gcnt, NE);
    bin_scan_kernel<<<1, 1024, 0, stream>>>(gcnt, gstart, gcursor);
    bin_scatter_kernel<<<(NE + 4095) / 4096, 256, 0, stream>>>(esrc, edst, gcursor, elist, NE);
    bucket_csr_kernel<<<NBUCK, 256, 0, stream>>>(elist, gstart, ssrc, offs);

    compose_kernel<<<C + 1, C, 0, stream>>>(w2_l, w2_r, b2, wd1, bd1, wcomp, bcomp);
    pack_w1_kernel<<<128, 256, 0, stream>>>(w1_l, w1_r, w1h, w1l);
    pack_w2_kernel<<<256, 256, 0, stream>>>(wcomp, w2h, w2l);

    gather_mean_kernel<<<6144, 256, 0, stream>>>(x, offs, ssrc, mean);
    mfma_transform_kernel<2, 8, 1><<<(NN + 127) / 128, 256, 0, stream>>>(
        mean, x, w1h, w1l, b1, h1, nullptr);
    gather_mean_kernel<<<6144, 256, 0, stream>>>(h1, offs, ssrc, mean);
    // outputs alias inputs: a -> mean buffer, b -> h1 buffer (safe: each wave
    // reads only its own 16 rows in the K-loop before its epilogue writes them)
    mfma_transform_kernel<1, 16, 0><<<(NN + 63) / 64, 256, 0, stream>>>(
        mean, h1, w2h, w2l, bcomp, mean, h1);

    decode_kernel<<<4096, 256, 0, stream>>>(mean, h1, pu, pv, wd2, bd2, (float*)d_out);
}

// Round 10
// 380.106 us; speedup vs baseline: 7.6689x; 1.3635x over previous
//
#include <hip/hip_runtime.h>
#include <hip/hip_bf16.h>

#define NN 100000
#define NE 1600000
#define NP 500000
#define C 128
#define NBUCK 782              // buckets of 128 dst nodes: 782*128 = 100096 >= NN

typedef __attribute__((ext_vector_type(8))) short bf16x8;
typedef __attribute__((ext_vector_type(4))) float f32x4;
typedef _Float16 f16;
typedef __attribute__((ext_vector_type(4))) _Float16 f16x4;
typedef __attribute__((ext_vector_type(8))) _Float16 f16x8;

__device__ inline unsigned short bfbits(float x) {
    __hip_bfloat16 h = __float2bfloat16(x);
    union { __hip_bfloat16 h; unsigned short u; } v; v.h = h;
    return v.u;
}
__device__ inline float bf2f(unsigned short b) {
    return __uint_as_float(((unsigned)b) << 16);
}

__device__ inline void split8core(const float* xs, bf16x8& hi, bf16x8& lo) {
    union { unsigned short s[8]; bf16x8 v; } uh, ul;
#pragma unroll
    for (int j = 0; j < 8; ++j) {
        unsigned short h = bfbits(xs[j]);
        uh.s[j] = h;
        ul.s[j] = bfbits(xs[j] - bf2f(h));
    }
    hi = uh.v;
    lo = ul.v;
}

// split 8 consecutive f32 into bf16 hi + bf16 lo fragments
__device__ inline void split8(const float* p, bf16x8& hi, bf16x8& lo) {
    f32x4 a = *(const f32x4*)p;
    f32x4 b = *(const f32x4*)(p + 4);
    float xs[8] = {a.x, a.y, a.z, a.w, b.x, b.y, b.z, b.w};
    split8core(xs, hi, lo);
}

// split 8 consecutive f16 into bf16 hi + bf16 lo (exact: f16 has 11 mant bits)
__device__ inline void split8h(const f16* p, bf16x8& hi, bf16x8& lo) {
    f16x8 v = *(const f16x8*)p;
    float xs[8];
#pragma unroll
    for (int j = 0; j < 8; ++j) xs[j] = (float)v[j];
    split8core(xs, hi, lo);
}

// ---------- f32 -> f16 conversion ----------
__global__ __launch_bounds__(256) void f32_to_f16_kernel(
        const float* __restrict__ in, f16* __restrict__ out, int n4) {
    int i = blockIdx.x * 256 + threadIdx.x;
    if (i < n4) {
        float4 v = *(const float4*)&in[i * 4];
        f16x4 h = {(f16)v.x, (f16)v.y, (f16)v.z, (f16)v.w};
        *(f16x4*)&out[i * 4] = h;
    }
}

// ---------- bucket histogram (LDS-staged) ----------
__global__ __launch_bounds__(256) void bin_count_kernel(
        const int* __restrict__ dst, int* __restrict__ gcnt, int nE) {
    __shared__ int h[NBUCK];
    int tid = threadIdx.x;
    for (int i = tid; i < NBUCK; i += 256) h[i] = 0;
    __syncthreads();
    int base = blockIdx.x * 8192;
#pragma unroll
    for (int j = 0; j < 32; ++j) {
        int e = base + tid + j * 256;
        if (e < nE) atomicAdd(&h[dst[e] >> 7], 1);
    }
    __syncthreads();
    for (int i = tid; i < NBUCK; i += 256)
        if (h[i]) atomicAdd(&gcnt[i], h[i]);
}

// ---------- scan bucket counts (one block) ----------
__global__ __launch_bounds__(1024) void bin_scan_kernel(
        const int* __restrict__ gcnt, int* __restrict__ gstart,
        int* __restrict__ gcursor) {
    __shared__ int s[1024];
    int tid = threadIdx.x;
    int v = (tid < NBUCK) ? gcnt[tid] : 0;
    s[tid] = v;
    __syncthreads();
    for (int off = 1; off < 1024; off <<= 1) {
        int t = (tid >= off) ? s[tid - off] : 0;
        __syncthreads();
        s[tid] += t;
        __syncthreads();
    }
    int excl = s[tid] - v;
    if (tid < NBUCK) { gstart[tid] = excl; gcursor[tid] = excl; }
    if (tid == NBUCK - 1) gstart[NBUCK] = excl + v;
}

// ---------- LDS-staged multisplit scatter: coalesced bucket-grouped writes ----------
__global__ __launch_bounds__(256) void bin_scatter_kernel(
        const int* __restrict__ src, const int* __restrict__ dst,
        int* __restrict__ gcursor, unsigned* __restrict__ elist, int nE) {
    __shared__ unsigned stage[4096];
    __shared__ unsigned short sbkt[4096];
    __shared__ int h[NBUCK];
    __shared__ int ex[NBUCK];
    __shared__ int gb[NBUCK];
    __shared__ int psum[256];
    int tid = threadIdx.x;
    for (int i = tid; i < NBUCK; i += 256) h[i] = 0;
    __syncthreads();
    int base = blockIdx.x * 4096;
    unsigned pk[16]; int bk[16];
#pragma unroll
    for (int j = 0; j < 16; ++j) {
        int e = base + tid + j * 256;
        bool ok = e < nE;
        int d = ok ? dst[e] : 0;
        int s = ok ? src[e] : 0;
        bk[j] = ok ? (d >> 7) : -1;
        pk[j] = ((unsigned)(d & 127) << 17) | (unsigned)s;
        if (ok) atomicAdd(&h[bk[j]], 1);
    }
    __syncthreads();
    int lo = tid * 4;
    int c4[4]; int sum = 0;
#pragma unroll
    for (int j = 0; j < 4; ++j) {
        int idx = lo + j;
        c4[j] = (idx < NBUCK) ? h[idx] : 0;
        sum += c4[j];
    }
    psum[tid] = sum;
    __syncthreads();
    for (int off = 1; off < 256; off <<= 1) {
        int t = (tid >= off) ? psum[tid - off] : 0;
        __syncthreads();
        psum[tid] += t;
        __syncthreads();
    }
    int run = psum[tid] - sum;
#pragma unroll
    for (int j = 0; j < 4; ++j) {
        int idx = lo + j;
        if (idx < NBUCK) ex[idx] = run;
        run += c4[j];
    }
    __syncthreads();
    for (int i = tid; i < NBUCK; i += 256)
        if (h[i] > 0) gb[i] = atomicAdd(&gcursor[i], h[i]);
    for (int i = tid; i < NBUCK; i += 256) h[i] = 0;
    __syncthreads();
#pragma unroll
    for (int j = 0; j < 16; ++j) {
        if (bk[j] >= 0) {
            int r = ex[bk[j]] + atomicAdd(&h[bk[j]], 1);
            stage[r] = pk[j];
            sbkt[r] = (unsigned short)bk[j];
        }
    }
    __syncthreads();
    int tot = min(4096, nE - base);
    for (int i = tid; i < tot; i += 256) {
        int b = sbkt[i];
        elist[gb[b] + (i - ex[b])] = stage[i];
    }
}

// ---------- per-bucket counting sort -> exact per-node CSR + offs ----------
__global__ __launch_bounds__(256) void bucket_csr_kernel(
        const unsigned* __restrict__ elist, const int* __restrict__ gstart,
        int* __restrict__ ssrc, int* __restrict__ offs) {
    __shared__ int cnt[128];
    __shared__ int sc[128];
    int tid = threadIdx.x;
    int b = blockIdx.x;
    if (tid < 128) cnt[tid] = 0;
    __syncthreads();
    int s = gstart[b], e = gstart[b + 1];
    for (int i = s + tid; i < e; i += 256)
        atomicAdd(&cnt[(elist[i] >> 17) & 127], 1);
    __syncthreads();
    int v = 0;
    if (tid < 128) { v = cnt[tid]; sc[tid] = v; }
    __syncthreads();
    for (int off = 1; off < 128; off <<= 1) {
        int t = 0;
        if (tid < 128 && tid >= off) t = sc[tid - off];
        __syncthreads();
        if (tid < 128) sc[tid] += t;
        __syncthreads();
    }
    if (tid < 128) {
        int start = s + sc[tid] - v;
        cnt[tid] = start;
        int node = b * 128 + tid;
        if (node < NN) offs[node] = start;
    }
    if (b == NBUCK - 1 && tid == 0) offs[NN] = NE;
    __syncthreads();
    for (int i = s + tid; i < e; i += 256) {
        unsigned p = elist[i];
        int r = (p >> 17) & 127;
        int pos = atomicAdd(&cnt[r], 1);
        ssrc[pos] = (int)(p & 0x1FFFF);
    }
}

// ---------- compose decode projection into layer-2 weights ----------
__global__ void compose_kernel(const float* __restrict__ w2l, const float* __restrict__ w2r,
                               const float* __restrict__ b2,
                               const float* __restrict__ wd1, const float* __restrict__ bd1,
                               float* __restrict__ wcomp, float* __restrict__ bcomp) {
    int c = threadIdx.x;
    int k = blockIdx.x;
    if (k < C) {
        float wma = 0, wmb = 0, wha = 0, whb = 0;
        for (int j = 0; j < C; ++j) {
            float wt = wd1[j * C + c];
            float wb = wd1[(C + j) * C + c];
            float l = w2l[k * C + j];
            float r = w2r[k * C + j];
            wma += l * wt; wmb += l * wb;
            wha += r * wt; whb += r * wb;
        }
        wcomp[0 * C * C + k * C + c] = wma;
        wcomp[1 * C * C + k * C + c] = wha;
        wcomp[2 * C * C + k * C + c] = wmb;
        wcomp[3 * C * C + k * C + c] = whb;
    } else {
        float ba = bd1[c], bb = 0;
        for (int j = 0; j < C; ++j) {
            float bj = b2[j];
            ba += bj * wd1[j * C + c];
            bb += bj * wd1[(C + j) * C + c];
        }
        bcomp[c] = ba;
        bcomp[C + c] = bb;
    }
}

// ---------- pack W1=[wl;wr] (K=256,N=128) into B-fragment layout, bf16 hi/lo ----------
__global__ void pack_w1_kernel(const float* __restrict__ wl, const float* __restrict__ wr,
                               short* __restrict__ Wh, short* __restrict__ Wl) {
    int t = blockIdx.x * 256 + threadIdx.x;
    int j = t & 7, l = (t >> 3) & 63;
    int kf = (t >> 9) & 7;
    int nf = t >> 12;
    int k = kf * 32 + ((l >> 4) << 3) + j;
    int n = nf * 16 + (l & 15);
    float w = (k < C) ? wl[k * C + n] : wr[(k - C) * C + n];
    unsigned short h = bfbits(w);
    Wh[t] = (short)h;
    Wl[t] = (short)bfbits(w - bf2f(h));
}

// ---------- pack composed W2 (K=256,N=256) from wcomp ----------
__global__ void pack_w2_kernel(const float* __restrict__ wcomp,
                               short* __restrict__ Wh, short* __restrict__ Wl) {
    int t = blockIdx.x * 256 + threadIdx.x;
    int j = t & 7, l = (t >> 3) & 63;
    int kf = (t >> 9) & 7;
    int nf = t >> 12;
    int k = kf * 32 + ((l >> 4) << 3) + j;
    int n = nf * 16 + (l & 15);
    int sel = (k >= C ? 1 : 0) + (n >= C ? 2 : 0);
    float w = wcomp[sel * C * C + (k & (C - 1)) * C + (n & (C - 1))];
    unsigned short h = bfbits(w);
    Wh[t] = (short)h;
    Wl[t] = (short)bfbits(w - bf2f(h));
}

// ---------- gather mean (f16 rows): half-wave (32 lanes x f16x4) per node ----------
__global__ __launch_bounds__(256) void gather_mean_f16_kernel(
        const f16* __restrict__ xin, const int* __restrict__ offs,
        const int* __restrict__ ssrc, f16* __restrict__ mean) {
    int gid = blockIdx.x * 256 + threadIdx.x;
    int hw = gid >> 5;
    int lane = threadIdx.x & 31;
    int nhw = (gridDim.x * 256) >> 5;
    for (int n = hw; n < NN; n += nhw) {
        int start = offs[n];
        int end = offs[n + 1];
        float4 acc = make_float4(0.f, 0.f, 0.f, 0.f);
        int e = start;
        for (; e + 7 < end; e += 8) {
            f16x4 v[8];
#pragma unroll
            for (int u = 0; u < 8; ++u)
                v[u] = *(const f16x4*)(xin + (size_t)ssrc[e + u] * C + lane * 4);
#pragma unroll
            for (int u = 0; u < 8; ++u) {
                acc.x += (float)v[u][0]; acc.y += (float)v[u][1];
                acc.z += (float)v[u][2]; acc.w += (float)v[u][3];
            }
        }
        for (; e < end; ++e) {
            f16x4 v = *(const f16x4*)(xin + (size_t)ssrc[e] * C + lane * 4);
            acc.x += (float)v[0]; acc.y += (float)v[1];
            acc.z += (float)v[2]; acc.w += (float)v[3];
        }
        float inv = 1.0f / fmaxf((float)(end - start), 1.0f);
        f16x4 m = {(f16)(acc.x * inv), (f16)(acc.y * inv),
                   (f16)(acc.z * inv), (f16)(acc.w * inv)};
        *(f16x4*)(mean + (size_t)n * C + lane * 4) = m;
    }
}

// ---------- MFMA transform: Y[NN x NF*16] = [A0|A1][NN x 256] @ W + bias ----------
// A0 = f16 mean rows; A1 = f32 (layer1: x) or f16 (layer2: h1) per A1F16.
// Outputs f16. MS*NF*4 acc VGPRs kept <=64 -> 4 waves/SIMD.
template<int MS, int NF, int RELU, int A1F16>
__global__ __launch_bounds__(256, 4) void mfma_transform_kernel(
        const f16* A0, const void* A1v,
        const short* __restrict__ Bh, const short* __restrict__ Bl,
        const float* __restrict__ bias,
        f16* O0, f16* O1) {
    constexpr int KF = 8;
    int tid = threadIdx.x;
    int w = tid >> 6, l = tid & 63;
    int m0 = blockIdx.x * (64 * MS) + w * (MS * 16);
    int lr = l & 15;
    int lk = (l >> 4) * 8;

    f32x4 acc[MS][NF];
#pragma unroll
    for (int ms = 0; ms < MS; ++ms)
#pragma unroll
        for (int nf = 0; nf < NF; ++nf)
            acc[ms][nf] = (f32x4){0.0f, 0.0f, 0.0f, 0.0f};

    const bf16x8* Bhp = (const bf16x8*)Bh;
    const bf16x8* Blp = (const bf16x8*)Bl;

#pragma unroll
    for (int kf = 0; kf < KF; ++kf) {
        int kofs = (kf & 3) * 32 + lk;
        bf16x8 ah[MS], al[MS];
#pragma unroll
        for (int ms = 0; ms < MS; ++ms) {
            int r = m0 + ms * 16 + lr;
            r = (r < NN) ? r : (NN - 1);
            if (kf < 4) {
                split8h(A0 + (size_t)r * C + kofs, ah[ms], al[ms]);
            } else if (A1F16) {
                split8h((const f16*)A1v + (size_t)r * C + kofs, ah[ms], al[ms]);
            } else {
                split8((const float*)A1v + (size_t)r * C + kofs, ah[ms], al[ms]);
            }
        }
#pragma unroll
        for (int nf = 0; nf < NF; ++nf) {
            bf16x8 bh = Bhp[(nf * KF + kf) * 64 + l];
            bf16x8 bl = Blp[(nf * KF + kf) * 64 + l];
#pragma unroll
            for (int ms = 0; ms < MS; ++ms) {
                acc[ms][nf] = __builtin_amdgcn_mfma_f32_16x16x32_bf16(ah[ms], bh, acc[ms][nf], 0, 0, 0);
                acc[ms][nf] = __builtin_amdgcn_mfma_f32_16x16x32_bf16(al[ms], bh, acc[ms][nf], 0, 0, 0);
                acc[ms][nf] = __builtin_amdgcn_mfma_f32_16x16x32_bf16(ah[ms], bl, acc[ms][nf], 0, 0, 0);
            }
        }
    }

#pragma unroll
    for (int nf = 0; nf < NF; ++nf) {
        int col = nf * 16 + lr;
        float bv = bias[col];
        f16* O = (NF == 8) ? O0 : ((nf < 8) ? O0 : O1);
        int c = (nf & 7) * 16 + lr;
#pragma unroll
        for (int ms = 0; ms < MS; ++ms) {
#pragma unroll
            for (int i = 0; i < 4; ++i) {
                int r = m0 + ms * 16 + (l >> 4) * 4 + i;
                if (r < NN) {
                    float v = acc[ms][nf][i] + bv;
                    if (RELU) v = fmaxf(v, 0.0f);
                    O[(size_t)r * C + c] = (f16)v;
                }
            }
        }
    }
}

// ---------- decode (f16 a/b): half-wave per pair, 2 pairs in flight ----------
__global__ __launch_bounds__(256) void decode_kernel(
        const f16* __restrict__ a, const f16* __restrict__ b,
        const int* __restrict__ pu, const int* __restrict__ pv,
        const float* __restrict__ wd2, const float* __restrict__ bd2,
        float* __restrict__ out) {
    int gid = blockIdx.x * 256 + threadIdx.x;
    int hw = gid >> 5;
    int lane = threadIdx.x & 31;
    int nhw = (gridDim.x * 256) >> 5;
    float4 w2 = *(const float4*)&wd2[lane * 4];
    float bout = bd2[0];
    for (int p = hw; p < NP; p += 2 * nhw) {
        int p2 = p + nhw;
        bool ok2 = p2 < NP;
        int u1 = pu[p], v1 = pv[p];
        int u2 = ok2 ? pu[p2] : 0, v2 = ok2 ? pv[p2] : 0;
        f16x4 a1 = *(const f16x4*)(a + (size_t)u1 * C + lane * 4);
        f16x4 b1 = *(const f16x4*)(b + (size_t)v1 * C + lane * 4);
        f16x4 a2 = *(const f16x4*)(a + (size_t)u2 * C + lane * 4);
        f16x4 b2 = *(const f16x4*)(b + (size_t)v2 * C + lane * 4);
        float s1 = fmaxf((float)a1[0] + (float)b1[0], 0.0f) * w2.x
                 + fmaxf((float)a1[1] + (float)b1[1], 0.0f) * w2.y
                 + fmaxf((float)a1[2] + (float)b1[2], 0.0f) * w2.z
                 + fmaxf((float)a1[3] + (float)b1[3], 0.0f) * w2.w;
        float s2 = fmaxf((float)a2[0] + (float)b2[0], 0.0f) * w2.x
                 + fmaxf((float)a2[1] + (float)b2[1], 0.0f) * w2.y
                 + fmaxf((float)a2[2] + (float)b2[2], 0.0f) * w2.z
                 + fmaxf((float)a2[3] + (float)b2[3], 0.0f) * w2.w;
#pragma unroll
        for (int off = 16; off; off >>= 1) {
            s1 += __shfl_down(s1, off, 32);
            s2 += __shfl_down(s2, off, 32);
        }
        if (lane == 0) {
            out[p] = s1 + bout;
            if (ok2) out[p2] = s2 + bout;
        }
    }
}

extern "C" void kernel_launch(void* const* d_in, const int* in_sizes, int n_in,
                              void* d_out, int out_size, void* d_ws, size_t ws_size,
                              hipStream_t stream) {
    const float* x    = (const float*)d_in[0];
    const float* w1_l = (const float*)d_in[1];
    const float* b1   = (const float*)d_in[2];
    const float* w1_r = (const float*)d_in[3];
    const float* w2_l = (const float*)d_in[4];
    const float* b2   = (const float*)d_in[5];
    const float* w2_r = (const float*)d_in[6];
    const float* wd1  = (const float*)d_in[7];
    const float* bd1  = (const float*)d_in[8];
    const float* wd2  = (const float*)d_in[9];
    const float* bd2  = (const float*)d_in[10];
    const int* edge_index = (const int*)d_in[11];
    const int* edge_pairs = (const int*)d_in[12];

    const int* esrc = edge_index;
    const int* edst = edge_index + NE;
    const int* pu = edge_pairs;
    const int* pv = edge_pairs + NP;

    // ws: gcnt|gstart|gcursor|offs | elist | ssrc | xh | mean_h | h1h | a_h | b_h | wcomp | bcomp | packs  (~142 MB)
    int* gcnt    = (int*)d_ws;
    int* gstart  = gcnt + 1024;
    int* gcursor = gstart + 1024;
    int* offs    = gcursor + 1024;
    unsigned* elist = (unsigned*)(offs + ((NN + 1 + 255) & ~255));
    int* ssrc    = (int*)(elist + NE);
    f16* xh      = (f16*)(ssrc + ((NE + 255) & ~255));
    f16* mean_h  = xh + (size_t)NN * C;
    f16* h1h     = mean_h + (size_t)NN * C;
    f16* a_h     = h1h + (size_t)NN * C;
    f16* b_h     = a_h + (size_t)NN * C;
    float* wcomp = (float*)(b_h + (size_t)NN * C);
    float* bcomp = wcomp + 4 * C * C;
    short* w1h = (short*)(bcomp + 2 * C);
    short* w1l = w1h + 256 * 128;
    short* w2h = w1l + 256 * 128;
    short* w2l = w2h + 256 * 256;

    hipMemsetAsync(gcnt, 0, sizeof(int) * 1024, stream);

    bin_count_kernel<<<(NE + 8191) / 8192, 256, 0, stream>>>(edst, gcnt, NE);
    bin_scan_kernel<<<1, 1024, 0, stream>>>(gcnt, gstart, gcursor);
    bin_scatter_kernel<<<(NE + 4095) / 4096, 256, 0, stream>>>(esrc, edst, gcursor, elist, NE);
    bucket_csr_kernel<<<NBUCK, 256, 0, stream>>>(elist, gstart, ssrc, offs);

    compose_kernel<<<C + 1, C, 0, stream>>>(w2_l, w2_r, b2, wd1, bd1, wcomp, bcomp);
    pack_w1_kernel<<<128, 256, 0, stream>>>(w1_l, w1_r, w1h, w1l);
    pack_w2_kernel<<<256, 256, 0, stream>>>(wcomp, w2h, w2l);

    f32_to_f16_kernel<<<(NN * C / 4 + 255) / 256, 256, 0, stream>>>(x, xh, NN * C / 4);

    gather_mean_f16_kernel<<<6144, 256, 0, stream>>>(xh, offs, ssrc, mean_h);
    mfma_transform_kernel<2, 8, 1, 0><<<(NN + 127) / 128, 256, 0, stream>>>(
        mean_h, (const void*)x, w1h, w1l, b1, h1h, nullptr);
    gather_mean_f16_kernel<<<6144, 256, 0, stream>>>(h1h, offs, ssrc, mean_h);
    mfma_transform_kernel<1, 16, 0, 1><<<(NN + 63) / 64, 256, 0, stream>>>(
        mean_h, (const void*)h1h, w2h, w2l, bcomp, a_h, b_h);

    decode_kernel<<<4096, 256, 0, stream>>>(a_h, b_h, pu, pv, wd2, bd2, (float*)d_out);
}

// Round 11
// 353.779 us; speedup vs baseline: 8.2396x; 1.0744x over previous
//
#include <hip/hip_runtime.h>
#include <hip/hip_bf16.h>

#define NN 100000
#define NE 1600000
#define NP 500000
#define C 128
#define NBUCK 782              // buckets of 128 dst nodes: 782*128 = 100096 >= NN

typedef __attribute__((ext_vector_type(4))) float f32x4;
typedef _Float16 f16;
typedef __attribute__((ext_vector_type(4))) _Float16 f16x4;
typedef __attribute__((ext_vector_type(8))) _Float16 f16x8;

// ---------- f32 -> f16 conversion ----------
__global__ __launch_bounds__(256) void f32_to_f16_kernel(
        const float* __restrict__ in, f16* __restrict__ out, int n4) {
    int i = blockIdx.x * 256 + threadIdx.x;
    if (i < n4) {
        float4 v = *(const float4*)&in[i * 4];
        f16x4 h = {(f16)v.x, (f16)v.y, (f16)v.z, (f16)v.w};
        *(f16x4*)&out[i * 4] = h;
    }
}

// ---------- bucket histogram (LDS-staged) ----------
__global__ __launch_bounds__(256) void bin_count_kernel(
        const int* __restrict__ dst, int* __restrict__ gcnt, int nE) {
    __shared__ int h[NBUCK];
    int tid = threadIdx.x;
    for (int i = tid; i < NBUCK; i += 256) h[i] = 0;
    __syncthreads();
    int base = blockIdx.x * 8192;
#pragma unroll
    for (int j = 0; j < 32; ++j) {
        int e = base + tid + j * 256;
        if (e < nE) atomicAdd(&h[dst[e] >> 7], 1);
    }
    __syncthreads();
    for (int i = tid; i < NBUCK; i += 256)
        if (h[i]) atomicAdd(&gcnt[i], h[i]);
}

// ---------- scan bucket counts (one block) ----------
__global__ __launch_bounds__(1024) void bin_scan_kernel(
        const int* __restrict__ gcnt, int* __restrict__ gstart,
        int* __restrict__ gcursor) {
    __shared__ int s[1024];
    int tid = threadIdx.x;
    int v = (tid < NBUCK) ? gcnt[tid] : 0;
    s[tid] = v;
    __syncthreads();
    for (int off = 1; off < 1024; off <<= 1) {
        int t = (tid >= off) ? s[tid - off] : 0;
        __syncthreads();
        s[tid] += t;
        __syncthreads();
    }
    int excl = s[tid] - v;
    if (tid < NBUCK) { gstart[tid] = excl; gcursor[tid] = excl; }
    if (tid == NBUCK - 1) gstart[NBUCK] = excl + v;
}

// ---------- LDS-staged multisplit scatter: coalesced bucket-grouped writes ----------
__global__ __launch_bounds__(256) void bin_scatter_kernel(
        const int* __restrict__ src, const int* __restrict__ dst,
        int* __restrict__ gcursor, unsigned* __restrict__ elist, int nE) {
    __shared__ unsigned stage[4096];
    __shared__ unsigned short sbkt[4096];
    __shared__ int h[NBUCK];
    __shared__ int ex[NBUCK];
    __shared__ int gb[NBUCK];
    __shared__ int psum[256];
    int tid = threadIdx.x;
    for (int i = tid; i < NBUCK; i += 256) h[i] = 0;
    __syncthreads();
    int base = blockIdx.x * 4096;
    unsigned pk[16]; int bk[16];
#pragma unroll
    for (int j = 0; j < 16; ++j) {
        int e = base + tid + j * 256;
        bool ok = e < nE;
        int d = ok ? dst[e] : 0;
        int s = ok ? src[e] : 0;
        bk[j] = ok ? (d >> 7) : -1;
        pk[j] = ((unsigned)(d & 127) << 17) | (unsigned)s;
        if (ok) atomicAdd(&h[bk[j]], 1);
    }
    __syncthreads();
    int lo = tid * 4;
    int c4[4]; int sum = 0;
#pragma unroll
    for (int j = 0; j < 4; ++j) {
        int idx = lo + j;
        c4[j] = (idx < NBUCK) ? h[idx] : 0;
        sum += c4[j];
    }
    psum[tid] = sum;
    __syncthreads();
    for (int off = 1; off < 256; off <<= 1) {
        int t = (tid >= off) ? psum[tid - off] : 0;
        __syncthreads();
        psum[tid] += t;
        __syncthreads();
    }
    int run = psum[tid] - sum;
#pragma unroll
    for (int j = 0; j < 4; ++j) {
        int idx = lo + j;
        if (idx < NBUCK) ex[idx] = run;
        run += c4[j];
    }
    __syncthreads();
    for (int i = tid; i < NBUCK; i += 256)
        if (h[i] > 0) gb[i] = atomicAdd(&gcursor[i], h[i]);
    for (int i = tid; i < NBUCK; i += 256) h[i] = 0;
    __syncthreads();
#pragma unroll
    for (int j = 0; j < 16; ++j) {
        if (bk[j] >= 0) {
            int r = ex[bk[j]] + atomicAdd(&h[bk[j]], 1);
            stage[r] = pk[j];
            sbkt[r] = (unsigned short)bk[j];
        }
    }
    __syncthreads();
    int tot = min(4096, nE - base);
    for (int i = tid; i < tot; i += 256) {
        int b = sbkt[i];
        elist[gb[b] + (i - ex[b])] = stage[i];
    }
}

// ---------- per-bucket counting sort -> exact per-node CSR + offs ----------
__global__ __launch_bounds__(256) void bucket_csr_kernel(
        const unsigned* __restrict__ elist, const int* __restrict__ gstart,
        int* __restrict__ ssrc, int* __restrict__ offs) {
    __shared__ int cnt[128];
    __shared__ int sc[128];
    int tid = threadIdx.x;
    int b = blockIdx.x;
    if (tid < 128) cnt[tid] = 0;
    __syncthreads();
    int s = gstart[b], e = gstart[b + 1];
    for (int i = s + tid; i < e; i += 256)
        atomicAdd(&cnt[(elist[i] >> 17) & 127], 1);
    __syncthreads();
    int v = 0;
    if (tid < 128) { v = cnt[tid]; sc[tid] = v; }
    __syncthreads();
    for (int off = 1; off < 128; off <<= 1) {
        int t = 0;
        if (tid < 128 && tid >= off) t = sc[tid - off];
        __syncthreads();
        if (tid < 128) sc[tid] += t;
        __syncthreads();
    }
    if (tid < 128) {
        int start = s + sc[tid] - v;
        cnt[tid] = start;
        int node = b * 128 + tid;
        if (node < NN) offs[node] = start;
    }
    if (b == NBUCK - 1 && tid == 0) offs[NN] = NE;
    __syncthreads();
    for (int i = s + tid; i < e; i += 256) {
        unsigned p = elist[i];
        int r = (p >> 17) & 127;
        int pos = atomicAdd(&cnt[r], 1);
        ssrc[pos] = (int)(p & 0x1FFFF);
    }
}

// ---------- compose decode projection into layer-2 weights ----------
__global__ void compose_kernel(const float* __restrict__ w2l, const float* __restrict__ w2r,
                               const float* __restrict__ b2,
                               const float* __restrict__ wd1, const float* __restrict__ bd1,
                               float* __restrict__ wcomp, float* __restrict__ bcomp) {
    int c = threadIdx.x;
    int k = blockIdx.x;
    if (k < C) {
        float wma = 0, wmb = 0, wha = 0, whb = 0;
        for (int j = 0; j < C; ++j) {
            float wt = wd1[j * C + c];
            float wb = wd1[(C + j) * C + c];
            float l = w2l[k * C + j];
            float r = w2r[k * C + j];
            wma += l * wt; wmb += l * wb;
            wha += r * wt; whb += r * wb;
        }
        wcomp[0 * C * C + k * C + c] = wma;
        wcomp[1 * C * C + k * C + c] = wha;
        wcomp[2 * C * C + k * C + c] = wmb;
        wcomp[3 * C * C + k * C + c] = whb;
    } else {
        float ba = bd1[c], bb = 0;
        for (int j = 0; j < C; ++j) {
            float bj = b2[j];
            ba += bj * wd1[j * C + c];
            bb += bj * wd1[(C + j) * C + c];
        }
        bcomp[c] = ba;
        bcomp[C + c] = bb;
    }
}

// ---------- pack W1=[wl;wr] (K=256,N=128) into B-frag layout, f16 hi/lo ----------
// flat idx = ((nf*8 + kf)*64 + l)*8 + j ; element = W[kf*32 + (l>>4)*8 + j][nf*16 + (l&15)]
__global__ void pack_w1_kernel(const float* __restrict__ wl, const float* __restrict__ wr,
                               f16* __restrict__ Wh, f16* __restrict__ Wl) {
    int t = blockIdx.x * 256 + threadIdx.x;   // [0, 256*128)
    int j = t & 7, l = (t >> 3) & 63;
    int kf = (t >> 9) & 7;
    int nf = t >> 12;
    int k = kf * 32 + ((l >> 4) << 3) + j;
    int n = nf * 16 + (l & 15);
    float w = (k < C) ? wl[k * C + n] : wr[(k - C) * C + n];
    f16 h = (f16)w;
    Wh[t] = h;
    Wl[t] = (f16)(w - (float)h);
}

// ---------- pack composed W2 (K=256,N=256) from wcomp, f16 hi/lo ----------
__global__ void pack_w2_kernel(const float* __restrict__ wcomp,
                               f16* __restrict__ Wh, f16* __restrict__ Wl) {
    int t = blockIdx.x * 256 + threadIdx.x;   // [0, 256*256)
    int j = t & 7, l = (t >> 3) & 63;
    int kf = (t >> 9) & 7;
    int nf = t >> 12;
    int k = kf * 32 + ((l >> 4) << 3) + j;
    int n = nf * 16 + (l & 15);
    int sel = (k >= C ? 1 : 0) + (n >= C ? 2 : 0);
    float w = wcomp[sel * C * C + (k & (C - 1)) * C + (n & (C - 1))];
    f16 h = (f16)w;
    Wh[t] = h;
    Wl[t] = (f16)(w - (float)h);
}

// ---------- gather mean (f16 rows): half-wave (32 lanes x f16x4) per node ----------
__global__ __launch_bounds__(256) void gather_mean_f16_kernel(
        const f16* __restrict__ xin, const int* __restrict__ offs,
        const int* __restrict__ ssrc, f16* __restrict__ mean) {
    int gid = blockIdx.x * 256 + threadIdx.x;
    int hw = gid >> 5;
    int lane = threadIdx.x & 31;
    int nhw = (gridDim.x * 256) >> 5;
    for (int n = hw; n < NN; n += nhw) {
        int start = offs[n];
        int end = offs[n + 1];
        float4 acc = make_float4(0.f, 0.f, 0.f, 0.f);
        int e = start;
        for (; e + 7 < end; e += 8) {
            f16x4 v[8];
#pragma unroll
            for (int u = 0; u < 8; ++u)
                v[u] = *(const f16x4*)(xin + (size_t)ssrc[e + u] * C + lane * 4);
#pragma unroll
            for (int u = 0; u < 8; ++u) {
                acc.x += (float)v[u][0]; acc.y += (float)v[u][1];
                acc.z += (float)v[u][2]; acc.w += (float)v[u][3];
            }
        }
        for (; e < end; ++e) {
            f16x4 v = *(const f16x4*)(xin + (size_t)ssrc[e] * C + lane * 4);
            acc.x += (float)v[0]; acc.y += (float)v[1];
            acc.z += (float)v[2]; acc.w += (float)v[3];
        }
        float inv = 1.0f / fmaxf((float)(end - start), 1.0f);
        f16x4 m = {(f16)(acc.x * inv), (f16)(acc.y * inv),
                   (f16)(acc.z * inv), (f16)(acc.w * inv)};
        *(f16x4*)(mean + (size_t)n * C + lane * 4) = m;
    }
}

// ---------- f16 MFMA transform: Y = [A0|A1] @ (Wh+Wl) + bias ----------
// A exact f16 (no split); weights f16 hi+lo -> 2 MFMA per product.
// MS=4 row-frags/wave (block = 256 rows), NF=4 col-frags/block;
// gridDim.y = N-chunks of 64 cols. acc = 64 VGPR -> 4 waves/SIMD.
template<int NFT, int RELU>
__global__ __launch_bounds__(256, 4) void mfma_transform_f16_kernel(
        const f16* __restrict__ A0, const f16* __restrict__ A1,
        const f16* __restrict__ Bh, const f16* __restrict__ Bl,
        const float* __restrict__ bias,
        f16* O0, f16* O1) {
    constexpr int KF = 8;
    constexpr int MS = 4;
    constexpr int NF = 4;
    int tid = threadIdx.x;
    int w = tid >> 6, l = tid & 63;
    int m0 = blockIdx.x * (64 * MS) + w * (MS * 16);
    int nf0 = blockIdx.y * NF;       // global col-frag base
    int lr = l & 15;
    int lk = (l >> 4) * 8;

    f32x4 acc[MS][NF];
#pragma unroll
    for (int ms = 0; ms < MS; ++ms)
#pragma unroll
        for (int nf = 0; nf < NF; ++nf)
            acc[ms][nf] = (f32x4){0.0f, 0.0f, 0.0f, 0.0f};

    const f16x8* Bhp = (const f16x8*)Bh;
    const f16x8* Blp = (const f16x8*)Bl;

#pragma unroll
    for (int kf = 0; kf < KF; ++kf) {
        const f16* Asrc = (kf < 4) ? A0 : A1;
        int kofs = (kf & 3) * 32 + lk;
        f16x8 a[MS];
#pragma unroll
        for (int ms = 0; ms < MS; ++ms) {
            int r = m0 + ms * 16 + lr;
            r = (r < NN) ? r : (NN - 1);
            a[ms] = *(const f16x8*)(Asrc + (size_t)r * C + kofs);
        }
#pragma unroll
        for (int nf = 0; nf < NF; ++nf) {
            f16x8 bh = Bhp[((nf0 + nf) * KF + kf) * 64 + l];
            f16x8 bl = Blp[((nf0 + nf) * KF + kf) * 64 + l];
#pragma unroll
            for (int ms = 0; ms < MS; ++ms) {
                acc[ms][nf] = __builtin_amdgcn_mfma_f32_16x16x32_f16(a[ms], bh, acc[ms][nf], 0, 0, 0);
                acc[ms][nf] = __builtin_amdgcn_mfma_f32_16x16x32_f16(a[ms], bl, acc[ms][nf], 0, 0, 0);
            }
        }
    }

    // epilogue: C/D layout col = lane&15, row = (lane>>4)*4 + i
#pragma unroll
    for (int nf = 0; nf < NF; ++nf) {
        int nfg = nf0 + nf;
        float bv = bias[nfg * 16 + lr];
        f16* O = (NFT == 8) ? O0 : ((nfg < 8) ? O0 : O1);
        int c = ((NFT == 8) ? nfg : (nfg & 7)) * 16 + lr;
#pragma unroll
        for (int ms = 0; ms < MS; ++ms) {
#pragma unroll
            for (int i = 0; i < 4; ++i) {
                int r = m0 + ms * 16 + (l >> 4) * 4 + i;
                if (r < NN) {
                    float v = acc[ms][nf][i] + bv;
                    if (RELU) v = fmaxf(v, 0.0f);
                    O[(size_t)r * C + c] = (f16)v;
                }
            }
        }
    }
}

// ---------- decode (f16 a/b): half-wave per pair, 2 pairs in flight ----------
__global__ __launch_bounds__(256) void decode_kernel(
        const f16* __restrict__ a, const f16* __restrict__ b,
        const int* __restrict__ pu, const int* __restrict__ pv,
        const float* __restrict__ wd2, const float* __restrict__ bd2,
        float* __restrict__ out) {
    int gid = blockIdx.x * 256 + threadIdx.x;
    int hw = gid >> 5;
    int lane = threadIdx.x & 31;
    int nhw = (gridDim.x * 256) >> 5;
    float4 w2 = *(const float4*)&wd2[lane * 4];
    float bout = bd2[0];
    for (int p = hw; p < NP; p += 2 * nhw) {
        int p2 = p + nhw;
        bool ok2 = p2 < NP;
        int u1 = pu[p], v1 = pv[p];
        int u2 = ok2 ? pu[p2] : 0, v2 = ok2 ? pv[p2] : 0;
        f16x4 a1 = *(const f16x4*)(a + (size_t)u1 * C + lane * 4);
        f16x4 b1 = *(const f16x4*)(b + (size_t)v1 * C + lane * 4);
        f16x4 a2 = *(const f16x4*)(a + (size_t)u2 * C + lane * 4);
        f16x4 b2 = *(const f16x4*)(b + (size_t)v2 * C + lane * 4);
        float s1 = fmaxf((float)a1[0] + (float)b1[0], 0.0f) * w2.x
                 + fmaxf((float)a1[1] + (float)b1[1], 0.0f) * w2.y
                 + fmaxf((float)a1[2] + (float)b1[2], 0.0f) * w2.z
                 + fmaxf((float)a1[3] + (float)b1[3], 0.0f) * w2.w;
        float s2 = fmaxf((float)a2[0] + (float)b2[0], 0.0f) * w2.x
                 + fmaxf((float)a2[1] + (float)b2[1], 0.0f) * w2.y
                 + fmaxf((float)a2[2] + (float)b2[2], 0.0f) * w2.z
                 + fmaxf((float)a2[3] + (float)b2[3], 0.0f) * w2.w;
#pragma unroll
        for (int off = 16; off; off >>= 1) {
            s1 += __shfl_down(s1, off, 32);
            s2 += __shfl_down(s2, off, 32);
        }
        if (lane == 0) {
            out[p] = s1 + bout;
            if (ok2) out[p2] = s2 + bout;
        }
    }
}

extern "C" void kernel_launch(void* const* d_in, const int* in_sizes, int n_in,
                              void* d_out, int out_size, void* d_ws, size_t ws_size,
                              hipStream_t stream) {
    const float* x    = (const float*)d_in[0];
    const float* w1_l = (const float*)d_in[1];
    const float* b1   = (const float*)d_in[2];
    const float* w1_r = (const float*)d_in[3];
    const float* w2_l = (const float*)d_in[4];
    const float* b2   = (const float*)d_in[5];
    const float* w2_r = (const float*)d_in[6];
    const float* wd1  = (const float*)d_in[7];
    const float* bd1  = (const float*)d_in[8];
    const float* wd2  = (const float*)d_in[9];
    const float* bd2  = (const float*)d_in[10];
    const int* edge_index = (const int*)d_in[11];
    const int* edge_pairs = (const int*)d_in[12];

    const int* esrc = edge_index;
    const int* edst = edge_index + NE;
    const int* pu = edge_pairs;
    const int* pv = edge_pairs + NP;

    // ws: gcnt|gstart|gcursor|offs | elist | ssrc | xh | mean_h | h1h | a_h | b_h | wcomp | bcomp | packs  (~142 MB)
    int* gcnt    = (int*)d_ws;
    int* gstart  = gcnt + 1024;
    int* gcursor = gstart + 1024;
    int* offs    = gcursor + 1024;
    unsigned* elist = (unsigned*)(offs + ((NN + 1 + 255) & ~255));
    int* ssrc    = (int*)(elist + NE);
    f16* xh      = (f16*)(ssrc + ((NE + 255) & ~255));
    f16* mean_h  = xh + (size_t)NN * C;
    f16* h1h     = mean_h + (size_t)NN * C;
    f16* a_h     = h1h + (size_t)NN * C;
    f16* b_h     = a_h + (size_t)NN * C;
    float* wcomp = (float*)(b_h + (size_t)NN * C);
    float* bcomp = wcomp + 4 * C * C;
    f16* w1h = (f16*)(bcomp + 2 * C);
    f16* w1l = w1h + 256 * 128;
    f16* w2h = w1l + 256 * 128;
    f16* w2l = w2h + 256 * 256;

    hipMemsetAsync(gcnt, 0, sizeof(int) * 1024, stream);

    bin_count_kernel<<<(NE + 8191) / 8192, 256, 0, stream>>>(edst, gcnt, NE);
    bin_scan_kernel<<<1, 1024, 0, stream>>>(gcnt, gstart, gcursor);
    bin_scatter_kernel<<<(NE + 4095) / 4096, 256, 0, stream>>>(esrc, edst, gcursor, elist, NE);
    bucket_csr_kernel<<<NBUCK, 256, 0, stream>>>(elist, gstart, ssrc, offs);

    compose_kernel<<<C + 1, C, 0, stream>>>(w2_l, w2_r, b2, wd1, bd1, wcomp, bcomp);
    pack_w1_kernel<<<128, 256, 0, stream>>>(w1_l, w1_r, w1h, w1l);
    pack_w2_kernel<<<256, 256, 0, stream>>>(wcomp, w2h, w2l);

    f32_to_f16_kernel<<<(NN * C / 4 + 255) / 256, 256, 0, stream>>>(x, xh, NN * C / 4);

    int rblocks = (NN + 255) / 256;   // 391
    gather_mean_f16_kernel<<<6144, 256, 0, stream>>>(xh, offs, ssrc, mean_h);
    mfma_transform_f16_kernel<8, 1><<<dim3(rblocks, 2), 256, 0, stream>>>(
        mean_h, xh, w1h, w1l, b1, h1h, nullptr);
    gather_mean_f16_kernel<<<6144, 256, 0, stream>>>(h1h, offs, ssrc, mean_h);
    mfma_transform_f16_kernel<16, 0><<<dim3(rblocks, 4), 256, 0, stream>>>(
        mean_h, h1h, w2h, w2l, bcomp, a_h, b_h);

    decode_kernel<<<4096, 256, 0, stream>>>(a_h, b_h, pu, pv, wd2, bd2, (float*)d_out);
}